// Round 7
// baseline (1062.905 us; speedup 1.0000x reference)
//
#include <hip/hip_runtime.h>

// ---------------------------------------------------------------------------
// CausalSelfAttention (GPT-2 style), MI355X / gfx950
//   qkv GEMM writes Q,K rows and V transposed (vt[bh][d][t])
//   flash attention: swapped-QK^T 32x32x16 MFMA, in-register softmax,
//   8-wave blocks with 2-way split-K (flash-decoding combine through LDS),
//   register prefetch of next K/V tile, native bf16 packing, setprio.
// B=2 T=4096 C=768 H=12 hd=64
// ---------------------------------------------------------------------------

#define DEVFN __device__ __forceinline__

typedef __attribute__((ext_vector_type(8)))  short   short8;
typedef __attribute__((ext_vector_type(4)))  short   short4v;
typedef __attribute__((ext_vector_type(8)))  __bf16  bf16x8;
typedef __attribute__((ext_vector_type(4)))  float   f32x4;
typedef __attribute__((ext_vector_type(16))) float   f32x16;

constexpr int BATCH = 2;
constexpr int T     = 4096;
constexpr int CDIM  = 768;
constexpr int NH    = 12;
constexpr int HD    = 64;
constexpr int M_TOK = BATCH * T;   // 8192
constexpr int N_QKV = 3 * CDIM;    // 2304
constexpr int N_QK  = 2 * CDIM;    // 1536
constexpr float QSCALE = 0.125f * 1.44269504f;  // 1/sqrt(64) * log2(e)

DEVFN short f2bf(float f) {            // RNE float -> bf16 bits
  unsigned u = __builtin_bit_cast(unsigned, f);
  u += 0x7fffu + ((u >> 16) & 1u);
  return (short)(u >> 16);
}
DEVFN float bf2f(short s) {
  return __builtin_bit_cast(float, ((unsigned)(unsigned short)s) << 16);
}
DEVFN short nbf(float f) {             // native cast (compiler -> v_cvt_pk)
  return __builtin_bit_cast(short, (__bf16)f);
}
DEVFN unsigned pack2(float a, float b) {  // 2 f32 -> packed bf16x2
  union { __bf16 h[2]; unsigned u; } x;
  x.h[0] = (__bf16)a; x.h[1] = (__bf16)b;
  return x.u;
}
DEVFN f32x4 mfma16(short8 a, short8 b, f32x4 c) {
  return __builtin_amdgcn_mfma_f32_16x16x32_bf16(
      __builtin_bit_cast(bf16x8, a), __builtin_bit_cast(bf16x8, b), c, 0, 0, 0);
}
DEVFN f32x16 mfma32(short8 a, short8 b, f32x16 c) {
  return __builtin_amdgcn_mfma_f32_32x32x16_bf16(
      __builtin_bit_cast(bf16x8, a), __builtin_bit_cast(bf16x8, b), c, 0, 0, 0);
}
DEVFN short8 mk8(unsigned w0, unsigned w1, unsigned w2, unsigned w3) {
  union { unsigned u[4]; short8 s; } x;
  x.u[0] = w0; x.u[1] = w1; x.u[2] = w2; x.u[3] = w3;
  return x.s;
}

// ---------------------------------------------------------------------------
__global__ void cast_f32_bf16(const float* __restrict__ in,
                              short* __restrict__ out, int n) {
  int i = (blockIdx.x * blockDim.x + threadIdx.x) * 4;
  if (i >= n) return;
  f32x4 v = *reinterpret_cast<const f32x4*>(in + i);
  short4v o;
#pragma unroll
  for (int j = 0; j < 4; ++j) o[j] = f2bf(v[j]);
  *reinterpret_cast<short4v*>(out + i) = o;
}

__global__ void transpose_cast(const float* __restrict__ in,
                               short* __restrict__ out, int R, int Cc) {
  __shared__ float tile[32][33];
  int c0 = blockIdx.x * 32, r0 = blockIdx.y * 32;
  int tx = threadIdx.x, ty = threadIdx.y;  // block (32, 8)
#pragma unroll
  for (int j = 0; j < 32; j += 8) {
    int r = r0 + ty + j, c = c0 + tx;
    tile[ty + j][tx] = (r < R && c < Cc) ? in[(size_t)r * Cc + c] : 0.f;
  }
  __syncthreads();
#pragma unroll
  for (int j = 0; j < 32; j += 8) {
    int r = r0 + tx, c = c0 + ty + j;
    if (c < Cc && r < R) out[(size_t)c * R + r] = f2bf(tile[tx][ty + j]);
  }
}

// ---------------------------------------------------------------------------
// GEMM: C[M][N] = A[M][K] @ Bt[N][K]^T + bias[N]
// MODE 0: f32 plain output.
// MODE 2: qkv split — cols [0,1536) -> qk bf16 [M][1536];
//         cols [1536,2304) (= V) -> vt bf16 [(b*NH+h)*64+d][T] (transposed).
// ---------------------------------------------------------------------------
template <int MODE>
__global__ __launch_bounds__(256)
void gemm_bt(const short* __restrict__ A, const short* __restrict__ Bt,
             const float* __restrict__ bias, float* __restrict__ Cf,
             short* __restrict__ qk_out, short* __restrict__ vt_out,
             int M, int N, int K) {
  constexpr int BM = 128, BN = 128, BK = 32, LDP = BK + 8;
  __shared__ short As[BM * LDP];
  __shared__ short Bs[BN * LDP];
  const int bm = blockIdx.x, bn = blockIdx.y;
  const int tid = threadIdx.x;
  const int lane = tid & 63, wid = tid >> 6;
  const int wm = wid >> 1, wn = wid & 1;
  const int lr = lane & 15, lh = lane >> 4;

  f32x4 acc[4][4] = {};

  const short* Abase = A + (size_t)(bm * BM) * K;
  const short* Bbase = Bt + (size_t)(bn * BN) * K;

  for (int k0 = 0; k0 < K; k0 += BK) {
    __syncthreads();
#pragma unroll
    for (int i = 0; i < 2; ++i) {
      int c = tid + i * 256;
      int row = c >> 2, col = (c & 3) << 3;
      *reinterpret_cast<short8*>(&As[row * LDP + col]) =
          *reinterpret_cast<const short8*>(Abase + (size_t)row * K + k0 + col);
      *reinterpret_cast<short8*>(&Bs[row * LDP + col]) =
          *reinterpret_cast<const short8*>(Bbase + (size_t)row * K + k0 + col);
    }
    __syncthreads();

    short8 af[4], bfr[4];
#pragma unroll
    for (int m = 0; m < 4; ++m)
      af[m] = *reinterpret_cast<const short8*>(
          &As[(wm * 64 + m * 16 + lr) * LDP + lh * 8]);
#pragma unroll
    for (int n = 0; n < 4; ++n)
      bfr[n] = *reinterpret_cast<const short8*>(
          &Bs[(wn * 64 + n * 16 + lr) * LDP + lh * 8]);
#pragma unroll
    for (int m = 0; m < 4; ++m)
#pragma unroll
      for (int n = 0; n < 4; ++n)
        acc[m][n] = mfma16(af[m], bfr[n], acc[m][n]);
  }

  // C/D layout: col = lane&15, row = 4*(lane>>4)+r
#pragma unroll
  for (int m = 0; m < 4; ++m) {
#pragma unroll
    for (int n = 0; n < 4; ++n) {
#pragma unroll
      for (int r = 0; r < 4; ++r) {
        int row = bm * BM + wm * 64 + m * 16 + lh * 4 + r;
        int col = bn * BN + wn * 64 + n * 16 + lr;
        float v = acc[m][n][r] + bias[col];
        if (MODE == 0) {
          Cf[(size_t)row * N + col] = v;
        } else {
          if (bn < 12) {  // Q,K region (boundary 1536 is tile-aligned)
            qk_out[(size_t)row * N_QK + col] = f2bf(v);
          } else {        // V region -> transposed store
            int hd_ = col - N_QK;
            int h = hd_ >> 6, d = hd_ & 63;
            int b_ = row >> 12, t_ = row & (T - 1);
            vt_out[(size_t)((b_ * NH + h) * HD + d) * T + t_] = f2bf(v);
          }
        }
      }
    }
  }
}

// ---------------------------------------------------------------------------
// Causal flash attention, swapped-QK^T 32x32 structure, 2-way split-K.
// Grid: (32, B*H) heavy-first. Block: 512 thr = 8 waves = 2 k-groups x 4.
// Group g handles k-tiles [g*(qb+1), (g+1)*(qb+1)); each wave owns 32 q-rows
// of the 128-row q-tile. Per 64-k tile: register-prefetched staging,
// S^T = mfma32(K, Q), merged online softmax in registers (shfl_xor 32),
// P packed to bf16 B-frags via native cvt + shfl_xor + select.
// K[k][d], V^T[d][k] in per-group LDS, XOR-swizzled write+read
// (byte ^= (row&7)<<4). Final flash-decoding combine through LDS.
// ---------------------------------------------------------------------------
__global__ __launch_bounds__(512, 8)
void attn_kernel(const short* __restrict__ qk, const short* __restrict__ vt,
                 short* __restrict__ y) {
  // staging: K[2][4096] shorts @ [0,16384), V[2][4096] @ [16384..)
  // reused after the k-loops as the split-K combine buffer (9216 floats).
  __shared__ short smem[18432];

  const int qb = 31 - (int)blockIdx.x;  // heavy blocks first
  const int bh = blockIdx.y;
  const int b = bh / NH, h = bh % NH;
  const int tid = threadIdx.x;
  const int gid = tid >> 8;             // split-K group
  const int tg  = tid & 255;            // thread id within group
  const int wv  = (tid >> 6) & 3;       // wave within group
  const int lane = tid & 63;
  const int c31 = lane & 31, hi = lane >> 5;
  const int wq = qb * 128 + wv * 32;    // wave's first q row
  const int qabs = wq + c31;            // lane's q column

  short* Kg = smem + gid * 4096;
  short* Vg = smem + 8192 + gid * 4096;

  const short* qk_b  = qk + (size_t)b * T * N_QK;
  const short* vt_bh = vt + (size_t)(bh * HD) * T;

  // staging geometry: 2 chunks of 16B per thread per tile (per group)
  const int ck0 = tg, ck1 = 256 + tg;
  const int row0 = ck0 >> 3, colB0 = (ck0 & 7) << 4;
  const int row1 = ck1 >> 3, colB1 = (ck1 & 7) << 4;
  const int lsw0 = (row0 * 128 + (colB0 ^ ((row0 & 7) << 4))) >> 1;
  const int lsw1 = (row1 * 128 + (colB1 ^ ((row1 & 7) << 4))) >> 1;
  const short* kp0 = qk_b + (size_t)row0 * N_QK + CDIM + h * HD + (colB0 >> 1);
  const short* kp1 = qk_b + (size_t)row1 * N_QK + CDIM + h * HD + (colB1 >> 1);
  const short* vp0 = vt_bh + (size_t)row0 * T + (colB0 >> 1);
  const short* vp1 = vt_bh + (size_t)row1 * T + (colB1 >> 1);

  const int swq = (c31 & 7) << 4;       // read-side swizzle XOR (bytes)

  // Q B-frags (lane: q=c31, d = ds*16 + 8*hi + i), scaled by QSCALE
  short8 qf[4];
  {
    const short* qp = qk_b + (size_t)qabs * N_QK + h * HD;
#pragma unroll
    for (int ds = 0; ds < 4; ++ds) {
      short8 raw = *reinterpret_cast<const short8*>(qp + ds * 16 + hi * 8);
#pragma unroll
      for (int i = 0; i < 8; ++i) raw[i] = nbf(bf2f(raw[i]) * QSCALE);
      qf[ds] = raw;
    }
  }

  f32x16 oacc[2];
#pragma unroll
  for (int dt = 0; dt < 2; ++dt)
#pragma unroll
    for (int r = 0; r < 16; ++r) oacc[dt][r] = 0.f;
  float mrow = -1e30f, lrow = 0.f;

  const int half = qb + 1;
  const int base = gid * half;          // this group's first k-tile

  // prologue: prefetch tile `base` into registers
  short8 kreg0 = *reinterpret_cast<const short8*>(kp0 + (size_t)base * 64 * N_QK);
  short8 kreg1 = *reinterpret_cast<const short8*>(kp1 + (size_t)base * 64 * N_QK);
  short8 vreg0 = *reinterpret_cast<const short8*>(vp0 + base * 64);
  short8 vreg1 = *reinterpret_cast<const short8*>(vp1 + base * 64);

  for (int i = 0; i < half; ++i) {
    const int t = base + i;
    __syncthreads();  // previous tile's readers done; prefetch landed
    *reinterpret_cast<short8*>(&Kg[lsw0]) = kreg0;
    *reinterpret_cast<short8*>(&Kg[lsw1]) = kreg1;
    *reinterpret_cast<short8*>(&Vg[lsw0]) = vreg0;
    *reinterpret_cast<short8*>(&Vg[lsw1]) = vreg1;
    __syncthreads();  // tile visible
    if (i + 1 < half) {  // issue next-tile loads; land during compute
      size_t ko = (size_t)(t + 1) * 64 * N_QK;
      int    vo = (t + 1) * 64;
      kreg0 = *reinterpret_cast<const short8*>(kp0 + ko);
      kreg1 = *reinterpret_cast<const short8*>(kp1 + ko);
      vreg0 = *reinterpret_cast<const short8*>(vp0 + vo);
      vreg1 = *reinterpret_cast<const short8*>(vp1 + vo);
    }

    const int ks = t * 64;
    if (ks > wq + 31) continue;  // wave fully above causal diagonal

    // S^T[64k][32q]: lane holds k-rows ks + 32*kk + (r&3)+8*(r>>2)+4*hi
    f32x16 s0, s1;
#pragma unroll
    for (int r = 0; r < 16; ++r) { s0[r] = 0.f; s1[r] = 0.f; }
    __builtin_amdgcn_s_setprio(1);
#pragma unroll
    for (int ds = 0; ds < 4; ++ds) {
      int cB = (ds * 32 + hi * 16) ^ swq;
      short8 kf0 = *reinterpret_cast<const short8*>(&Kg[(c31 * 128 + cB) >> 1]);
      short8 kf1 = *reinterpret_cast<const short8*>(
          &Kg[((32 + c31) * 128 + cB) >> 1]);
      s0 = mfma32(kf0, qf[ds], s0);
      s1 = mfma32(kf1, qf[ds], s1);
    }
    __builtin_amdgcn_s_setprio(0);

    if (ks + 63 > wq) {  // causal mask (wave-uniform branch)
#pragma unroll
      for (int r = 0; r < 16; ++r) {
        int kab = ks + (r & 3) + 8 * (r >> 2) + 4 * hi;
        if (kab > qabs) s0[r] = -1e30f;
        if (kab + 32 > qabs) s1[r] = -1e30f;
      }
    }

    // merged 64-k online softmax, exp2 domain (log2e folded into Q)
    float mx = fmaxf(s0[0], s1[0]);
#pragma unroll
    for (int r = 1; r < 16; ++r) mx = fmaxf(mx, fmaxf(s0[r], s1[r]));
    mx = fmaxf(mx, __shfl_xor(mx, 32));
    float mnew = fmaxf(mrow, mx);
    float alpha = exp2f(mrow - mnew);
    mrow = mnew;
    float psum = 0.f;
#pragma unroll
    for (int r = 0; r < 16; ++r) { s0[r] = exp2f(s0[r] - mnew); psum += s0[r]; }
#pragma unroll
    for (int r = 0; r < 16; ++r) { s1[r] = exp2f(s1[r] - mnew); psum += s1[r]; }
    psum += __shfl_xor(psum, 32);
    lrow = lrow * alpha + psum;
#pragma unroll
    for (int dt = 0; dt < 2; ++dt)
#pragma unroll
      for (int r = 0; r < 16; ++r) oacc[dt][r] *= alpha;

    // P -> bf16 PV B-frags (16 k per KT slice). Lane holds (rel to KT*16):
    //   lo: k0..3 = p[b..b+3], k8..11 = p[b+4..b+7]
    //   hi: k4..7 = p[b..b+3], k12..15 = p[b+4..b+7]
    // word w = (k_{8hi+2w}, k_{8hi+2w+1}):
    //   w0 = hi?partner(C):A   w1 = hi?partner(D):B
    //   w2 = hi?C:partner(A)   w3 = hi?D:partner(B)
#pragma unroll
    for (int KT = 0; KT < 4; ++KT) {
      const f32x16& p = (KT < 2) ? s0 : s1;
      const int bse = (KT & 1) * 8;
      unsigned Aw = pack2(p[bse + 0], p[bse + 1]);
      unsigned Bw = pack2(p[bse + 2], p[bse + 3]);
      unsigned Cw = pack2(p[bse + 4], p[bse + 5]);
      unsigned Dw = pack2(p[bse + 6], p[bse + 7]);
      unsigned As = __shfl_xor(Aw, 32);
      unsigned Bs = __shfl_xor(Bw, 32);
      unsigned Cs = __shfl_xor(Cw, 32);
      unsigned Ds = __shfl_xor(Dw, 32);
      short8 pf = mk8(hi ? Cs : Aw, hi ? Ds : Bw, hi ? Cw : As, hi ? Dw : Bs);
      int cB = (KT * 32 + hi * 16) ^ swq;
      __builtin_amdgcn_s_setprio(1);
#pragma unroll
      for (int dt = 0; dt < 2; ++dt) {
        short8 vf = *reinterpret_cast<const short8*>(
            &Vg[((dt * 32 + c31) * 128 + cB) >> 1]);
        oacc[dt] = mfma32(vf, pf, oacc[dt]);
      }
      __builtin_amdgcn_s_setprio(0);
    }
  }

  // ---- split-K combine (flash-decoding merge through LDS) ----
  __syncthreads();  // all staging reads done; smem reusable
  float* cmb = reinterpret_cast<float*>(smem);
  const int ci = (wv * 64 + lane) * 36;  // 36-float stride, 16B-aligned
  if (gid == 1) {
#pragma unroll
    for (int dt = 0; dt < 2; ++dt)
#pragma unroll
      for (int q4 = 0; q4 < 4; ++q4)
        *reinterpret_cast<f32x4*>(&cmb[ci + dt * 16 + q4 * 4]) = (f32x4){
            oacc[dt][q4 * 4 + 0], oacc[dt][q4 * 4 + 1],
            oacc[dt][q4 * 4 + 2], oacc[dt][q4 * 4 + 3]};
    cmb[ci + 32] = mrow;
    cmb[ci + 33] = lrow;
  }
  __syncthreads();
  if (gid == 0) {
    float m1 = cmb[ci + 32], l1 = cmb[ci + 33];
    float mm = fmaxf(mrow, m1);
    float a0 = exp2f(mrow - mm), a1 = exp2f(m1 - mm);
    float inv = 1.0f / (lrow * a0 + l1 * a1);
    // epilogue: O^T reg r -> d = dt*32 + (r&3)+8*(r>>2)+4*hi, q = c31
    short* yp = y + (size_t)(b * T + qabs) * CDIM + h * HD;
#pragma unroll
    for (int dt = 0; dt < 2; ++dt) {
#pragma unroll
      for (int qd = 0; qd < 4; ++qd) {
        f32x4 o1 = *reinterpret_cast<const f32x4*>(&cmb[ci + dt * 16 + qd * 4]);
        short4v o4;
#pragma unroll
        for (int e = 0; e < 4; ++e)
          o4[e] = nbf((oacc[dt][4 * qd + e] * a0 + o1[e] * a1) * inv);
        *reinterpret_cast<short4v*>(yp + dt * 32 + qd * 8 + hi * 4) = o4;
      }
    }
  }
}

// ---------------------------------------------------------------------------
extern "C" void kernel_launch(void* const* d_in, const int* in_sizes, int n_in,
                              void* d_out, int out_size, void* d_ws,
                              size_t ws_size, hipStream_t stream) {
  const float* x      = (const float*)d_in[0];
  const float* w_attn = (const float*)d_in[1];
  const float* b_attn = (const float*)d_in[2];
  const float* w_proj = (const float*)d_in[3];
  const float* b_proj = (const float*)d_in[4];
  float* out = (float*)d_out;

  // workspace (bf16 shorts); y reuses xb (dead after QKV GEMM)
  short* xb   = (short*)d_ws;                        // 8192*768
  short* watT = xb + (size_t)M_TOK * CDIM;           // 2304*768
  short* wpT  = watT + (size_t)N_QKV * CDIM;         // 768*768
  short* qkB  = wpT + (size_t)CDIM * CDIM;           // 8192*1536
  short* vtB  = qkB + (size_t)M_TOK * N_QK;          // 24*64*4096
  short* yb   = xb;

  {
    int n = M_TOK * CDIM;
    cast_f32_bf16<<<n / 4 / 256, 256, 0, stream>>>(x, xb, n);
  }
  transpose_cast<<<dim3(N_QKV / 32, CDIM / 32), dim3(32, 8), 0, stream>>>(
      w_attn, watT, CDIM, N_QKV);
  transpose_cast<<<dim3(CDIM / 32, CDIM / 32), dim3(32, 8), 0, stream>>>(
      w_proj, wpT, CDIM, CDIM);

  // qkv = x @ w_attn + b_attn   (Q,K -> qkB; V -> vtB transposed)
  gemm_bt<2><<<dim3(M_TOK / 128, N_QKV / 128), 256, 0, stream>>>(
      xb, watT, b_attn, nullptr, qkB, vtB, M_TOK, N_QKV, CDIM);

  attn_kernel<<<dim3(32, BATCH * NH), 512, 0, stream>>>(qkB, vtB, yb);

  // out = y @ w_proj + b_proj   (f32 out)
  gemm_bt<0><<<dim3(M_TOK / 128, CDIM / 128), 256, 0, stream>>>(
      yb, wpT, b_proj, out, nullptr, nullptr, M_TOK, CDIM, CDIM);
}

// Round 8
// 352.378 us; speedup vs baseline: 3.0164x; 3.0164x over previous
//
#include <hip/hip_runtime.h>

// ---------------------------------------------------------------------------
// CausalSelfAttention (GPT-2 style), MI355X / gfx950
//   qkv GEMM writes Q,K rows and V transposed (vt[bh][d][t])
//   flash attention: swapped-QK^T 32x32x16 MFMA, in-register softmax,
//   8-wave blocks with 2-way split-K (flash-decoding combine through LDS),
//   register prefetch of next K/V tile, native bf16 packing, setprio.
// B=2 T=4096 C=768 H=12 hd=64
// ---------------------------------------------------------------------------

#define DEVFN __device__ __forceinline__

typedef __attribute__((ext_vector_type(8)))  short   short8;
typedef __attribute__((ext_vector_type(4)))  short   short4v;
typedef __attribute__((ext_vector_type(8)))  __bf16  bf16x8;
typedef __attribute__((ext_vector_type(4)))  float   f32x4;
typedef __attribute__((ext_vector_type(16))) float   f32x16;

constexpr int BATCH = 2;
constexpr int T     = 4096;
constexpr int CDIM  = 768;
constexpr int NH    = 12;
constexpr int HD    = 64;
constexpr int M_TOK = BATCH * T;   // 8192
constexpr int N_QKV = 3 * CDIM;    // 2304
constexpr int N_QK  = 2 * CDIM;    // 1536
constexpr float QSCALE = 0.125f * 1.44269504f;  // 1/sqrt(64) * log2(e)

DEVFN short f2bf(float f) {            // RNE float -> bf16 bits
  unsigned u = __builtin_bit_cast(unsigned, f);
  u += 0x7fffu + ((u >> 16) & 1u);
  return (short)(u >> 16);
}
DEVFN float bf2f(short s) {
  return __builtin_bit_cast(float, ((unsigned)(unsigned short)s) << 16);
}
DEVFN short nbf(float f) {             // native cast (compiler -> v_cvt_pk)
  return __builtin_bit_cast(short, (__bf16)f);
}
DEVFN unsigned pack2(float a, float b) {  // 2 f32 -> packed bf16x2
  union { __bf16 h[2]; unsigned u; } x;
  x.h[0] = (__bf16)a; x.h[1] = (__bf16)b;
  return x.u;
}
DEVFN f32x4 mfma16(short8 a, short8 b, f32x4 c) {
  return __builtin_amdgcn_mfma_f32_16x16x32_bf16(
      __builtin_bit_cast(bf16x8, a), __builtin_bit_cast(bf16x8, b), c, 0, 0, 0);
}
DEVFN f32x16 mfma32(short8 a, short8 b, f32x16 c) {
  return __builtin_amdgcn_mfma_f32_32x32x16_bf16(
      __builtin_bit_cast(bf16x8, a), __builtin_bit_cast(bf16x8, b), c, 0, 0, 0);
}
DEVFN short8 mk8(unsigned w0, unsigned w1, unsigned w2, unsigned w3) {
  union { unsigned u[4]; short8 s; } x;
  x.u[0] = w0; x.u[1] = w1; x.u[2] = w2; x.u[3] = w3;
  return x.s;
}

// ---------------------------------------------------------------------------
__global__ void cast_f32_bf16(const float* __restrict__ in,
                              short* __restrict__ out, int n) {
  int i = (blockIdx.x * blockDim.x + threadIdx.x) * 4;
  if (i >= n) return;
  f32x4 v = *reinterpret_cast<const f32x4*>(in + i);
  short4v o;
#pragma unroll
  for (int j = 0; j < 4; ++j) o[j] = f2bf(v[j]);
  *reinterpret_cast<short4v*>(out + i) = o;
}

__global__ void transpose_cast(const float* __restrict__ in,
                               short* __restrict__ out, int R, int Cc) {
  __shared__ float tile[32][33];
  int c0 = blockIdx.x * 32, r0 = blockIdx.y * 32;
  int tx = threadIdx.x, ty = threadIdx.y;  // block (32, 8)
#pragma unroll
  for (int j = 0; j < 32; j += 8) {
    int r = r0 + ty + j, c = c0 + tx;
    tile[ty + j][tx] = (r < R && c < Cc) ? in[(size_t)r * Cc + c] : 0.f;
  }
  __syncthreads();
#pragma unroll
  for (int j = 0; j < 32; j += 8) {
    int r = r0 + tx, c = c0 + ty + j;
    if (c < Cc && r < R) out[(size_t)c * R + r] = f2bf(tile[tx][ty + j]);
  }
}

// ---------------------------------------------------------------------------
// GEMM: C[M][N] = A[M][K] @ Bt[N][K]^T + bias[N]
// MODE 0: f32 plain output.
// MODE 2: qkv split — cols [0,1536) -> qk bf16 [M][1536];
//         cols [1536,2304) (= V) -> vt bf16 [(b*NH+h)*64+d][T] (transposed).
// ---------------------------------------------------------------------------
template <int MODE>
__global__ __launch_bounds__(256)
void gemm_bt(const short* __restrict__ A, const short* __restrict__ Bt,
             const float* __restrict__ bias, float* __restrict__ Cf,
             short* __restrict__ qk_out, short* __restrict__ vt_out,
             int M, int N, int K) {
  constexpr int BM = 128, BN = 128, BK = 32, LDP = BK + 8;
  __shared__ short As[BM * LDP];
  __shared__ short Bs[BN * LDP];
  const int bm = blockIdx.x, bn = blockIdx.y;
  const int tid = threadIdx.x;
  const int lane = tid & 63, wid = tid >> 6;
  const int wm = wid >> 1, wn = wid & 1;
  const int lr = lane & 15, lh = lane >> 4;

  f32x4 acc[4][4] = {};

  const short* Abase = A + (size_t)(bm * BM) * K;
  const short* Bbase = Bt + (size_t)(bn * BN) * K;

  for (int k0 = 0; k0 < K; k0 += BK) {
    __syncthreads();
#pragma unroll
    for (int i = 0; i < 2; ++i) {
      int c = tid + i * 256;
      int row = c >> 2, col = (c & 3) << 3;
      *reinterpret_cast<short8*>(&As[row * LDP + col]) =
          *reinterpret_cast<const short8*>(Abase + (size_t)row * K + k0 + col);
      *reinterpret_cast<short8*>(&Bs[row * LDP + col]) =
          *reinterpret_cast<const short8*>(Bbase + (size_t)row * K + k0 + col);
    }
    __syncthreads();

    short8 af[4], bfr[4];
#pragma unroll
    for (int m = 0; m < 4; ++m)
      af[m] = *reinterpret_cast<const short8*>(
          &As[(wm * 64 + m * 16 + lr) * LDP + lh * 8]);
#pragma unroll
    for (int n = 0; n < 4; ++n)
      bfr[n] = *reinterpret_cast<const short8*>(
          &Bs[(wn * 64 + n * 16 + lr) * LDP + lh * 8]);
#pragma unroll
    for (int m = 0; m < 4; ++m)
#pragma unroll
      for (int n = 0; n < 4; ++n)
        acc[m][n] = mfma16(af[m], bfr[n], acc[m][n]);
  }

  // C/D layout: col = lane&15, row = 4*(lane>>4)+r
#pragma unroll
  for (int m = 0; m < 4; ++m) {
#pragma unroll
    for (int n = 0; n < 4; ++n) {
#pragma unroll
      for (int r = 0; r < 4; ++r) {
        int row = bm * BM + wm * 64 + m * 16 + lh * 4 + r;
        int col = bn * BN + wn * 64 + n * 16 + lr;
        float v = acc[m][n][r] + bias[col];
        if (MODE == 0) {
          Cf[(size_t)row * N + col] = v;
        } else {
          if (bn < 12) {  // Q,K region (boundary 1536 is tile-aligned)
            qk_out[(size_t)row * N_QK + col] = f2bf(v);
          } else {        // V region -> transposed store
            int hd_ = col - N_QK;
            int h = hd_ >> 6, d = hd_ & 63;
            int b_ = row >> 12, t_ = row & (T - 1);
            vt_out[(size_t)((b_ * NH + h) * HD + d) * T + t_] = f2bf(v);
          }
        }
      }
    }
  }
}

// ---------------------------------------------------------------------------
// Causal flash attention, swapped-QK^T 32x32 structure, 2-way split-K.
// Grid: (32, B*H) heavy-first. Block: 512 thr = 8 waves = 2 k-groups x 4.
// Group g handles k-tiles [g*(qb+1), (g+1)*(qb+1)); each wave owns 32 q-rows
// of the 128-row q-tile. Per 64-k tile: register-prefetched staging,
// S^T = mfma32(K, Q), merged online softmax in registers (shfl_xor 32),
// P packed to bf16 B-frags via native cvt + shfl_xor + select.
// K[k][d], V^T[d][k] in per-group LDS, XOR-swizzled write+read
// (byte ^= (row&7)<<4). Final flash-decoding combine through LDS.
// NOTE launch_bounds: 2nd arg = min waves/EU. 4 -> VGPR cap 128 (core loop
// needs ~100; 8 capped at 32 VGPR and spilled catastrophically in R7).
// ---------------------------------------------------------------------------
__global__ __launch_bounds__(512, 4)
void attn_kernel(const short* __restrict__ qk, const short* __restrict__ vt,
                 short* __restrict__ y) {
  // staging: K[2][4096] shorts @ [0,16384), V[2][4096] @ [16384..)
  // reused after the k-loops as the split-K combine buffer (9216 floats).
  __shared__ short smem[18432];

  const int qb = 31 - (int)blockIdx.x;  // heavy blocks first
  const int bh = blockIdx.y;
  const int b = bh / NH, h = bh % NH;
  const int tid = threadIdx.x;
  const int gid = tid >> 8;             // split-K group
  const int tg  = tid & 255;            // thread id within group
  const int wv  = (tid >> 6) & 3;       // wave within group
  const int lane = tid & 63;
  const int c31 = lane & 31, hi = lane >> 5;
  const int wq = qb * 128 + wv * 32;    // wave's first q row
  const int qabs = wq + c31;            // lane's q column

  short* Kg = smem + gid * 4096;
  short* Vg = smem + 8192 + gid * 4096;

  const short* qk_b  = qk + (size_t)b * T * N_QK;
  const short* vt_bh = vt + (size_t)(bh * HD) * T;

  // staging geometry: 2 chunks of 16B per thread per tile (per group)
  const int ck0 = tg, ck1 = 256 + tg;
  const int row0 = ck0 >> 3, colB0 = (ck0 & 7) << 4;
  const int row1 = ck1 >> 3, colB1 = (ck1 & 7) << 4;
  const int lsw0 = (row0 * 128 + (colB0 ^ ((row0 & 7) << 4))) >> 1;
  const int lsw1 = (row1 * 128 + (colB1 ^ ((row1 & 7) << 4))) >> 1;
  const short* kp0 = qk_b + (size_t)row0 * N_QK + CDIM + h * HD + (colB0 >> 1);
  const short* kp1 = qk_b + (size_t)row1 * N_QK + CDIM + h * HD + (colB1 >> 1);
  const short* vp0 = vt_bh + (size_t)row0 * T + (colB0 >> 1);
  const short* vp1 = vt_bh + (size_t)row1 * T + (colB1 >> 1);

  const int swq = (c31 & 7) << 4;       // read-side swizzle XOR (bytes)

  // Q B-frags (lane: q=c31, d = ds*16 + 8*hi + i), scaled by QSCALE
  short8 qf[4];
  {
    const short* qp = qk_b + (size_t)qabs * N_QK + h * HD;
#pragma unroll
    for (int ds = 0; ds < 4; ++ds) {
      short8 raw = *reinterpret_cast<const short8*>(qp + ds * 16 + hi * 8);
#pragma unroll
      for (int i = 0; i < 8; ++i) raw[i] = nbf(bf2f(raw[i]) * QSCALE);
      qf[ds] = raw;
    }
  }

  f32x16 oacc[2];
#pragma unroll
  for (int dt = 0; dt < 2; ++dt)
#pragma unroll
    for (int r = 0; r < 16; ++r) oacc[dt][r] = 0.f;
  float mrow = -1e30f, lrow = 0.f;

  const int half = qb + 1;
  const int base = gid * half;          // this group's first k-tile

  // prologue: prefetch tile `base` into registers
  short8 kreg0 = *reinterpret_cast<const short8*>(kp0 + (size_t)base * 64 * N_QK);
  short8 kreg1 = *reinterpret_cast<const short8*>(kp1 + (size_t)base * 64 * N_QK);
  short8 vreg0 = *reinterpret_cast<const short8*>(vp0 + base * 64);
  short8 vreg1 = *reinterpret_cast<const short8*>(vp1 + base * 64);

  for (int i = 0; i < half; ++i) {
    const int t = base + i;
    __syncthreads();  // previous tile's readers done; prefetch landed
    *reinterpret_cast<short8*>(&Kg[lsw0]) = kreg0;
    *reinterpret_cast<short8*>(&Kg[lsw1]) = kreg1;
    *reinterpret_cast<short8*>(&Vg[lsw0]) = vreg0;
    *reinterpret_cast<short8*>(&Vg[lsw1]) = vreg1;
    __syncthreads();  // tile visible
    if (i + 1 < half) {  // issue next-tile loads; land during compute
      size_t ko = (size_t)(t + 1) * 64 * N_QK;
      int    vo = (t + 1) * 64;
      kreg0 = *reinterpret_cast<const short8*>(kp0 + ko);
      kreg1 = *reinterpret_cast<const short8*>(kp1 + ko);
      vreg0 = *reinterpret_cast<const short8*>(vp0 + vo);
      vreg1 = *reinterpret_cast<const short8*>(vp1 + vo);
    }

    const int ks = t * 64;
    if (ks > wq + 31) continue;  // wave fully above causal diagonal

    // S^T[64k][32q]: lane holds k-rows ks + 32*kk + (r&3)+8*(r>>2)+4*hi
    f32x16 s0, s1;
#pragma unroll
    for (int r = 0; r < 16; ++r) { s0[r] = 0.f; s1[r] = 0.f; }
    __builtin_amdgcn_s_setprio(1);
#pragma unroll
    for (int ds = 0; ds < 4; ++ds) {
      int cB = (ds * 32 + hi * 16) ^ swq;
      short8 kf0 = *reinterpret_cast<const short8*>(&Kg[(c31 * 128 + cB) >> 1]);
      short8 kf1 = *reinterpret_cast<const short8*>(
          &Kg[((32 + c31) * 128 + cB) >> 1]);
      s0 = mfma32(kf0, qf[ds], s0);
      s1 = mfma32(kf1, qf[ds], s1);
    }
    __builtin_amdgcn_s_setprio(0);

    if (ks + 63 > wq) {  // causal mask (wave-uniform branch)
#pragma unroll
      for (int r = 0; r < 16; ++r) {
        int kab = ks + (r & 3) + 8 * (r >> 2) + 4 * hi;
        if (kab > qabs) s0[r] = -1e30f;
        if (kab + 32 > qabs) s1[r] = -1e30f;
      }
    }

    // merged 64-k online softmax, exp2 domain (log2e folded into Q)
    float mx = fmaxf(s0[0], s1[0]);
#pragma unroll
    for (int r = 1; r < 16; ++r) mx = fmaxf(mx, fmaxf(s0[r], s1[r]));
    mx = fmaxf(mx, __shfl_xor(mx, 32));
    float mnew = fmaxf(mrow, mx);
    float alpha = exp2f(mrow - mnew);
    mrow = mnew;
    float psum = 0.f;
#pragma unroll
    for (int r = 0; r < 16; ++r) { s0[r] = exp2f(s0[r] - mnew); psum += s0[r]; }
#pragma unroll
    for (int r = 0; r < 16; ++r) { s1[r] = exp2f(s1[r] - mnew); psum += s1[r]; }
    psum += __shfl_xor(psum, 32);
    lrow = lrow * alpha + psum;
#pragma unroll
    for (int dt = 0; dt < 2; ++dt)
#pragma unroll
      for (int r = 0; r < 16; ++r) oacc[dt][r] *= alpha;

    // P -> bf16 PV B-frags (16 k per KT slice). Lane holds (rel to KT*16):
    //   lo: k0..3 = p[b..b+3], k8..11 = p[b+4..b+7]
    //   hi: k4..7 = p[b..b+3], k12..15 = p[b+4..b+7]
    // word w = (k_{8hi+2w}, k_{8hi+2w+1}):
    //   w0 = hi?partner(C):A   w1 = hi?partner(D):B
    //   w2 = hi?C:partner(A)   w3 = hi?D:partner(B)
#pragma unroll
    for (int KT = 0; KT < 4; ++KT) {
      const f32x16& p = (KT < 2) ? s0 : s1;
      const int bse = (KT & 1) * 8;
      unsigned Aw = pack2(p[bse + 0], p[bse + 1]);
      unsigned Bw = pack2(p[bse + 2], p[bse + 3]);
      unsigned Cw = pack2(p[bse + 4], p[bse + 5]);
      unsigned Dw = pack2(p[bse + 6], p[bse + 7]);
      unsigned As = __shfl_xor(Aw, 32);
      unsigned Bs = __shfl_xor(Bw, 32);
      unsigned Cs = __shfl_xor(Cw, 32);
      unsigned Ds = __shfl_xor(Dw, 32);
      short8 pf = mk8(hi ? Cs : Aw, hi ? Ds : Bw, hi ? Cw : As, hi ? Dw : Bs);
      int cB = (KT * 32 + hi * 16) ^ swq;
      __builtin_amdgcn_s_setprio(1);
#pragma unroll
      for (int dt = 0; dt < 2; ++dt) {
        short8 vf = *reinterpret_cast<const short8*>(
            &Vg[((dt * 32 + c31) * 128 + cB) >> 1]);
        oacc[dt] = mfma32(vf, pf, oacc[dt]);
      }
      __builtin_amdgcn_s_setprio(0);
    }
  }

  // ---- split-K combine (flash-decoding merge through LDS) ----
  __syncthreads();  // all staging reads done; smem reusable
  float* cmb = reinterpret_cast<float*>(smem);
  const int ci = (wv * 64 + lane) * 36;  // 36-float stride, 16B-aligned
  if (gid == 1) {
#pragma unroll
    for (int dt = 0; dt < 2; ++dt)
#pragma unroll
      for (int q4 = 0; q4 < 4; ++q4)
        *reinterpret_cast<f32x4*>(&cmb[ci + dt * 16 + q4 * 4]) = (f32x4){
            oacc[dt][q4 * 4 + 0], oacc[dt][q4 * 4 + 1],
            oacc[dt][q4 * 4 + 2], oacc[dt][q4 * 4 + 3]};
    cmb[ci + 32] = mrow;
    cmb[ci + 33] = lrow;
  }
  __syncthreads();
  if (gid == 0) {
    float m1 = cmb[ci + 32], l1 = cmb[ci + 33];
    float mm = fmaxf(mrow, m1);
    float a0 = exp2f(mrow - mm), a1 = exp2f(m1 - mm);
    float inv = 1.0f / (lrow * a0 + l1 * a1);
    // epilogue: O^T reg r -> d = dt*32 + (r&3)+8*(r>>2)+4*hi, q = c31
    short* yp = y + (size_t)(b * T + qabs) * CDIM + h * HD;
#pragma unroll
    for (int dt = 0; dt < 2; ++dt) {
#pragma unroll
      for (int qd = 0; qd < 4; ++qd) {
        f32x4 o1 = *reinterpret_cast<const f32x4*>(&cmb[ci + dt * 16 + qd * 4]);
        short4v o4;
#pragma unroll
        for (int e = 0; e < 4; ++e)
          o4[e] = nbf((oacc[dt][4 * qd + e] * a0 + o1[e] * a1) * inv);
        *reinterpret_cast<short4v*>(yp + dt * 32 + qd * 8 + hi * 4) = o4;
      }
    }
  }
}

// ---------------------------------------------------------------------------
extern "C" void kernel_launch(void* const* d_in, const int* in_sizes, int n_in,
                              void* d_out, int out_size, void* d_ws,
                              size_t ws_size, hipStream_t stream) {
  const float* x      = (const float*)d_in[0];
  const float* w_attn = (const float*)d_in[1];
  const float* b_attn = (const float*)d_in[2];
  const float* w_proj = (const float*)d_in[3];
  const float* b_proj = (const float*)d_in[4];
  float* out = (float*)d_out;

  // workspace (bf16 shorts); y reuses xb (dead after QKV GEMM)
  short* xb   = (short*)d_ws;                        // 8192*768
  short* watT = xb + (size_t)M_TOK * CDIM;           // 2304*768
  short* wpT  = watT + (size_t)N_QKV * CDIM;         // 768*768
  short* qkB  = wpT + (size_t)CDIM * CDIM;           // 8192*1536
  short* vtB  = qkB + (size_t)M_TOK * N_QK;          // 24*64*4096
  short* yb   = xb;

  {
    int n = M_TOK * CDIM;
    cast_f32_bf16<<<n / 4 / 256, 256, 0, stream>>>(x, xb, n);
  }
  transpose_cast<<<dim3(N_QKV / 32, CDIM / 32), dim3(32, 8), 0, stream>>>(
      w_attn, watT, CDIM, N_QKV);
  transpose_cast<<<dim3(CDIM / 32, CDIM / 32), dim3(32, 8), 0, stream>>>(
      w_proj, wpT, CDIM, CDIM);

  // qkv = x @ w_attn + b_attn   (Q,K -> qkB; V -> vtB transposed)
  gemm_bt<2><<<dim3(M_TOK / 128, N_QKV / 128), 256, 0, stream>>>(
      xb, watT, b_attn, nullptr, qkB, vtB, M_TOK, N_QKV, CDIM);

  attn_kernel<<<dim3(32, BATCH * NH), 512, 0, stream>>>(qkB, vtB, yb);

  // out = y @ w_proj + b_proj   (f32 out)
  gemm_bt<0><<<dim3(M_TOK / 128, CDIM / 128), 256, 0, stream>>>(
      yb, wpT, b_proj, out, nullptr, nullptr, M_TOK, CDIM, CDIM);
}

// Round 9
// 338.905 us; speedup vs baseline: 3.1363x; 1.0398x over previous
//
#include <hip/hip_runtime.h>

// ---------------------------------------------------------------------------
// CausalSelfAttention (GPT-2 style), MI355X / gfx950
//   qkv GEMM writes Q,K rows and V transposed (vt[bh][d][t])
//   flash attention: swapped-QK^T 32x32x16 MFMA, in-register softmax,
//   8-wave blocks with 2-way split-K (flash-decoding combine through LDS),
//   register prefetch of next K/V tile, native bf16 packing, setprio.
// B=2 T=4096 C=768 H=12 hd=64
// ---------------------------------------------------------------------------

#define DEVFN __device__ __forceinline__

typedef __attribute__((ext_vector_type(8)))  short   short8;
typedef __attribute__((ext_vector_type(4)))  short   short4v;
typedef __attribute__((ext_vector_type(8)))  __bf16  bf16x8;
typedef __attribute__((ext_vector_type(4)))  float   f32x4;
typedef __attribute__((ext_vector_type(16))) float   f32x16;

constexpr int BATCH = 2;
constexpr int T     = 4096;
constexpr int CDIM  = 768;
constexpr int NH    = 12;
constexpr int HD    = 64;
constexpr int M_TOK = BATCH * T;   // 8192
constexpr int N_QKV = 3 * CDIM;    // 2304
constexpr int N_QK  = 2 * CDIM;    // 1536
constexpr float QSCALE = 0.125f * 1.44269504f;  // 1/sqrt(64) * log2(e)

DEVFN short f2bf(float f) {            // RNE float -> bf16 bits
  unsigned u = __builtin_bit_cast(unsigned, f);
  u += 0x7fffu + ((u >> 16) & 1u);
  return (short)(u >> 16);
}
DEVFN float bf2f(short s) {
  return __builtin_bit_cast(float, ((unsigned)(unsigned short)s) << 16);
}
DEVFN short nbf(float f) {             // native cast (compiler -> v_cvt_pk)
  return __builtin_bit_cast(short, (__bf16)f);
}
DEVFN unsigned pack2(float a, float b) {  // 2 f32 -> packed bf16x2
  union { __bf16 h[2]; unsigned u; } x;
  x.h[0] = (__bf16)a; x.h[1] = (__bf16)b;
  return x.u;
}
DEVFN f32x4 mfma16(short8 a, short8 b, f32x4 c) {
  return __builtin_amdgcn_mfma_f32_16x16x32_bf16(
      __builtin_bit_cast(bf16x8, a), __builtin_bit_cast(bf16x8, b), c, 0, 0, 0);
}
DEVFN f32x16 mfma32(short8 a, short8 b, f32x16 c) {
  return __builtin_amdgcn_mfma_f32_32x32x16_bf16(
      __builtin_bit_cast(bf16x8, a), __builtin_bit_cast(bf16x8, b), c, 0, 0, 0);
}
DEVFN short8 mk8(unsigned w0, unsigned w1, unsigned w2, unsigned w3) {
  union { unsigned u[4]; short8 s; } x;
  x.u[0] = w0; x.u[1] = w1; x.u[2] = w2; x.u[3] = w3;
  return x.s;
}

// ---------------------------------------------------------------------------
__global__ void cast_f32_bf16(const float* __restrict__ in,
                              short* __restrict__ out, int n) {
  int i = (blockIdx.x * blockDim.x + threadIdx.x) * 4;
  if (i >= n) return;
  f32x4 v = *reinterpret_cast<const f32x4*>(in + i);
  short4v o;
#pragma unroll
  for (int j = 0; j < 4; ++j) o[j] = f2bf(v[j]);
  *reinterpret_cast<short4v*>(out + i) = o;
}

__global__ void transpose_cast(const float* __restrict__ in,
                               short* __restrict__ out, int R, int Cc) {
  __shared__ float tile[32][33];
  int c0 = blockIdx.x * 32, r0 = blockIdx.y * 32;
  int tx = threadIdx.x, ty = threadIdx.y;  // block (32, 8)
#pragma unroll
  for (int j = 0; j < 32; j += 8) {
    int r = r0 + ty + j, c = c0 + tx;
    tile[ty + j][tx] = (r < R && c < Cc) ? in[(size_t)r * Cc + c] : 0.f;
  }
  __syncthreads();
#pragma unroll
  for (int j = 0; j < 32; j += 8) {
    int r = r0 + tx, c = c0 + ty + j;
    if (c < Cc && r < R) out[(size_t)c * R + r] = f2bf(tile[tx][ty + j]);
  }
}

// ---------------------------------------------------------------------------
// GEMM: C[M][N] = A[M][K] @ Bt[N][K]^T + bias[N]
// MODE 0: f32 plain output.
// MODE 2: qkv split — cols [0,1536) -> qk bf16 [M][1536];
//         cols [1536,2304) (= V) -> vt bf16 [(b*NH+h)*64+d][T] (transposed).
// ---------------------------------------------------------------------------
template <int MODE>
__global__ __launch_bounds__(256)
void gemm_bt(const short* __restrict__ A, const short* __restrict__ Bt,
             const float* __restrict__ bias, float* __restrict__ Cf,
             short* __restrict__ qk_out, short* __restrict__ vt_out,
             int M, int N, int K) {
  constexpr int BM = 128, BN = 128, BK = 32, LDP = BK + 8;
  __shared__ short As[BM * LDP];
  __shared__ short Bs[BN * LDP];
  const int bm = blockIdx.x, bn = blockIdx.y;
  const int tid = threadIdx.x;
  const int lane = tid & 63, wid = tid >> 6;
  const int wm = wid >> 1, wn = wid & 1;
  const int lr = lane & 15, lh = lane >> 4;

  f32x4 acc[4][4] = {};

  const short* Abase = A + (size_t)(bm * BM) * K;
  const short* Bbase = Bt + (size_t)(bn * BN) * K;

  for (int k0 = 0; k0 < K; k0 += BK) {
    __syncthreads();
#pragma unroll
    for (int i = 0; i < 2; ++i) {
      int c = tid + i * 256;
      int row = c >> 2, col = (c & 3) << 3;
      *reinterpret_cast<short8*>(&As[row * LDP + col]) =
          *reinterpret_cast<const short8*>(Abase + (size_t)row * K + k0 + col);
      *reinterpret_cast<short8*>(&Bs[row * LDP + col]) =
          *reinterpret_cast<const short8*>(Bbase + (size_t)row * K + k0 + col);
    }
    __syncthreads();

    short8 af[4], bfr[4];
#pragma unroll
    for (int m = 0; m < 4; ++m)
      af[m] = *reinterpret_cast<const short8*>(
          &As[(wm * 64 + m * 16 + lr) * LDP + lh * 8]);
#pragma unroll
    for (int n = 0; n < 4; ++n)
      bfr[n] = *reinterpret_cast<const short8*>(
          &Bs[(wn * 64 + n * 16 + lr) * LDP + lh * 8]);
#pragma unroll
    for (int m = 0; m < 4; ++m)
#pragma unroll
      for (int n = 0; n < 4; ++n)
        acc[m][n] = mfma16(af[m], bfr[n], acc[m][n]);
  }

  // C/D layout: col = lane&15, row = 4*(lane>>4)+r
#pragma unroll
  for (int m = 0; m < 4; ++m) {
#pragma unroll
    for (int n = 0; n < 4; ++n) {
#pragma unroll
      for (int r = 0; r < 4; ++r) {
        int row = bm * BM + wm * 64 + m * 16 + lh * 4 + r;
        int col = bn * BN + wn * 64 + n * 16 + lr;
        float v = acc[m][n][r] + bias[col];
        if (MODE == 0) {
          Cf[(size_t)row * N + col] = v;
        } else {
          if (bn < 12) {  // Q,K region (boundary 1536 is tile-aligned)
            qk_out[(size_t)row * N_QK + col] = f2bf(v);
          } else {        // V region -> transposed store
            int hd_ = col - N_QK;
            int h = hd_ >> 6, d = hd_ & 63;
            int b_ = row >> 12, t_ = row & (T - 1);
            vt_out[(size_t)((b_ * NH + h) * HD + d) * T + t_] = f2bf(v);
          }
        }
      }
    }
  }
}

// ---------------------------------------------------------------------------
// Causal flash attention, swapped-QK^T 32x32 structure, 2-way split-K.
// Grid: (32, B*H) heavy-first. Block: 512 thr = 8 waves = 2 k-groups x 4.
// Group g handles k-tiles [g*(qb+1), (g+1)*(qb+1)); each wave owns 32 q-rows
// of the 128-row q-tile. Per 64-k tile: register-prefetched staging,
// S^T = mfma32(K, Q), merged online softmax in registers (shfl_xor 32),
// P packed to bf16 B-frags via native cvt + shfl_xor + select.
// K[k][d], V^T[d][k] in per-group LDS, XOR-swizzled write+read
// (byte ^= (row&7)<<4). Final flash-decoding combine through LDS.
// NOTE launch_bounds 2nd arg — MEASURED on this toolchain to behave like
// CUDA's min BLOCKS/CU (not waves/EU): (512,8)->32 VGPR, (512,4)->64 VGPR
// (both spilled; R7 dur 1016us, R8 274us with 22MB scratch writes).
// (512,2) -> cap 128 VGPR; core loop needs ~100. Do not raise.
// ---------------------------------------------------------------------------
__global__ __launch_bounds__(512, 2)
void attn_kernel(const short* __restrict__ qk, const short* __restrict__ vt,
                 short* __restrict__ y) {
  // staging: K[2][4096] shorts @ [0,16384), V[2][4096] @ [16384..)
  // reused after the k-loops as the split-K combine buffer (9216 floats).
  __shared__ short smem[18432];

  const int qb = 31 - (int)blockIdx.x;  // heavy blocks first
  const int bh = blockIdx.y;
  const int b = bh / NH, h = bh % NH;
  const int tid = threadIdx.x;
  const int gid = tid >> 8;             // split-K group
  const int tg  = tid & 255;            // thread id within group
  const int wv  = (tid >> 6) & 3;       // wave within group
  const int lane = tid & 63;
  const int c31 = lane & 31, hi = lane >> 5;
  const int wq = qb * 128 + wv * 32;    // wave's first q row
  const int qabs = wq + c31;            // lane's q column

  short* Kg = smem + gid * 4096;
  short* Vg = smem + 8192 + gid * 4096;

  const short* qk_b  = qk + (size_t)b * T * N_QK;
  const short* vt_bh = vt + (size_t)(bh * HD) * T;

  // staging geometry: 2 chunks of 16B per thread per tile (per group)
  const int ck0 = tg, ck1 = 256 + tg;
  const int row0 = ck0 >> 3, colB0 = (ck0 & 7) << 4;
  const int row1 = ck1 >> 3, colB1 = (ck1 & 7) << 4;
  const int lsw0 = (row0 * 128 + (colB0 ^ ((row0 & 7) << 4))) >> 1;
  const int lsw1 = (row1 * 128 + (colB1 ^ ((row1 & 7) << 4))) >> 1;
  const short* kp0 = qk_b + (size_t)row0 * N_QK + CDIM + h * HD + (colB0 >> 1);
  const short* kp1 = qk_b + (size_t)row1 * N_QK + CDIM + h * HD + (colB1 >> 1);
  const short* vp0 = vt_bh + (size_t)row0 * T + (colB0 >> 1);
  const short* vp1 = vt_bh + (size_t)row1 * T + (colB1 >> 1);

  const int swq = (c31 & 7) << 4;       // read-side swizzle XOR (bytes)

  // Q B-frags (lane: q=c31, d = ds*16 + 8*hi + i), scaled by QSCALE
  short8 qf[4];
  {
    const short* qp = qk_b + (size_t)qabs * N_QK + h * HD;
#pragma unroll
    for (int ds = 0; ds < 4; ++ds) {
      short8 raw = *reinterpret_cast<const short8*>(qp + ds * 16 + hi * 8);
#pragma unroll
      for (int i = 0; i < 8; ++i) raw[i] = nbf(bf2f(raw[i]) * QSCALE);
      qf[ds] = raw;
    }
  }

  f32x16 oacc[2];
#pragma unroll
  for (int dt = 0; dt < 2; ++dt)
#pragma unroll
    for (int r = 0; r < 16; ++r) oacc[dt][r] = 0.f;
  float mrow = -1e30f, lrow = 0.f;

  const int half = qb + 1;
  const int base = gid * half;          // this group's first k-tile

  // prologue: prefetch tile `base` into registers
  short8 kreg0 = *reinterpret_cast<const short8*>(kp0 + (size_t)base * 64 * N_QK);
  short8 kreg1 = *reinterpret_cast<const short8*>(kp1 + (size_t)base * 64 * N_QK);
  short8 vreg0 = *reinterpret_cast<const short8*>(vp0 + base * 64);
  short8 vreg1 = *reinterpret_cast<const short8*>(vp1 + base * 64);

  for (int i = 0; i < half; ++i) {
    const int t = base + i;
    __syncthreads();  // previous tile's readers done; prefetch landed
    *reinterpret_cast<short8*>(&Kg[lsw0]) = kreg0;
    *reinterpret_cast<short8*>(&Kg[lsw1]) = kreg1;
    *reinterpret_cast<short8*>(&Vg[lsw0]) = vreg0;
    *reinterpret_cast<short8*>(&Vg[lsw1]) = vreg1;
    __syncthreads();  // tile visible
    if (i + 1 < half) {  // issue next-tile loads; land during compute
      size_t ko = (size_t)(t + 1) * 64 * N_QK;
      int    vo = (t + 1) * 64;
      kreg0 = *reinterpret_cast<const short8*>(kp0 + ko);
      kreg1 = *reinterpret_cast<const short8*>(kp1 + ko);
      vreg0 = *reinterpret_cast<const short8*>(vp0 + vo);
      vreg1 = *reinterpret_cast<const short8*>(vp1 + vo);
    }

    const int ks = t * 64;
    if (ks > wq + 31) continue;  // wave fully above causal diagonal

    // S^T[64k][32q]: lane holds k-rows ks + 32*kk + (r&3)+8*(r>>2)+4*hi
    f32x16 s0, s1;
#pragma unroll
    for (int r = 0; r < 16; ++r) { s0[r] = 0.f; s1[r] = 0.f; }
    __builtin_amdgcn_s_setprio(1);
#pragma unroll
    for (int ds = 0; ds < 4; ++ds) {
      int cB = (ds * 32 + hi * 16) ^ swq;
      short8 kf0 = *reinterpret_cast<const short8*>(&Kg[(c31 * 128 + cB) >> 1]);
      short8 kf1 = *reinterpret_cast<const short8*>(
          &Kg[((32 + c31) * 128 + cB) >> 1]);
      s0 = mfma32(kf0, qf[ds], s0);
      s1 = mfma32(kf1, qf[ds], s1);
    }
    __builtin_amdgcn_s_setprio(0);

    if (ks + 63 > wq) {  // causal mask (wave-uniform branch)
#pragma unroll
      for (int r = 0; r < 16; ++r) {
        int kab = ks + (r & 3) + 8 * (r >> 2) + 4 * hi;
        if (kab > qabs) s0[r] = -1e30f;
        if (kab + 32 > qabs) s1[r] = -1e30f;
      }
    }

    // merged 64-k online softmax, exp2 domain (log2e folded into Q)
    float mx = fmaxf(s0[0], s1[0]);
#pragma unroll
    for (int r = 1; r < 16; ++r) mx = fmaxf(mx, fmaxf(s0[r], s1[r]));
    mx = fmaxf(mx, __shfl_xor(mx, 32));
    float mnew = fmaxf(mrow, mx);
    float alpha = exp2f(mrow - mnew);
    mrow = mnew;
    float psum = 0.f;
#pragma unroll
    for (int r = 0; r < 16; ++r) { s0[r] = exp2f(s0[r] - mnew); psum += s0[r]; }
#pragma unroll
    for (int r = 0; r < 16; ++r) { s1[r] = exp2f(s1[r] - mnew); psum += s1[r]; }
    psum += __shfl_xor(psum, 32);
    lrow = lrow * alpha + psum;
#pragma unroll
    for (int dt = 0; dt < 2; ++dt)
#pragma unroll
      for (int r = 0; r < 16; ++r) oacc[dt][r] *= alpha;

    // P -> bf16 PV B-frags (16 k per KT slice). Lane holds (rel to KT*16):
    //   lo: k0..3 = p[b..b+3], k8..11 = p[b+4..b+7]
    //   hi: k4..7 = p[b..b+3], k12..15 = p[b+4..b+7]
    // word w = (k_{8hi+2w}, k_{8hi+2w+1}):
    //   w0 = hi?partner(C):A   w1 = hi?partner(D):B
    //   w2 = hi?C:partner(A)   w3 = hi?D:partner(B)
#pragma unroll
    for (int KT = 0; KT < 4; ++KT) {
      const f32x16& p = (KT < 2) ? s0 : s1;
      const int bse = (KT & 1) * 8;
      unsigned Aw = pack2(p[bse + 0], p[bse + 1]);
      unsigned Bw = pack2(p[bse + 2], p[bse + 3]);
      unsigned Cw = pack2(p[bse + 4], p[bse + 5]);
      unsigned Dw = pack2(p[bse + 6], p[bse + 7]);
      unsigned As = __shfl_xor(Aw, 32);
      unsigned Bs = __shfl_xor(Bw, 32);
      unsigned Cs = __shfl_xor(Cw, 32);
      unsigned Ds = __shfl_xor(Dw, 32);
      short8 pf = mk8(hi ? Cs : Aw, hi ? Ds : Bw, hi ? Cw : As, hi ? Dw : Bs);
      int cB = (KT * 32 + hi * 16) ^ swq;
      __builtin_amdgcn_s_setprio(1);
#pragma unroll
      for (int dt = 0; dt < 2; ++dt) {
        short8 vf = *reinterpret_cast<const short8*>(
            &Vg[((dt * 32 + c31) * 128 + cB) >> 1]);
        oacc[dt] = mfma32(vf, pf, oacc[dt]);
      }
      __builtin_amdgcn_s_setprio(0);
    }
  }

  // ---- split-K combine (flash-decoding merge through LDS) ----
  __syncthreads();  // all staging reads done; smem reusable
  float* cmb = reinterpret_cast<float*>(smem);
  const int ci = (wv * 64 + lane) * 36;  // 36-float stride, 16B-aligned
  if (gid == 1) {
#pragma unroll
    for (int dt = 0; dt < 2; ++dt)
#pragma unroll
      for (int q4 = 0; q4 < 4; ++q4)
        *reinterpret_cast<f32x4*>(&cmb[ci + dt * 16 + q4 * 4]) = (f32x4){
            oacc[dt][q4 * 4 + 0], oacc[dt][q4 * 4 + 1],
            oacc[dt][q4 * 4 + 2], oacc[dt][q4 * 4 + 3]};
    cmb[ci + 32] = mrow;
    cmb[ci + 33] = lrow;
  }
  __syncthreads();
  if (gid == 0) {
    float m1 = cmb[ci + 32], l1 = cmb[ci + 33];
    float mm = fmaxf(mrow, m1);
    float a0 = exp2f(mrow - mm), a1 = exp2f(m1 - mm);
    float inv = 1.0f / (lrow * a0 + l1 * a1);
    // epilogue: O^T reg r -> d = dt*32 + (r&3)+8*(r>>2)+4*hi, q = c31
    short* yp = y + (size_t)(b * T + qabs) * CDIM + h * HD;
#pragma unroll
    for (int dt = 0; dt < 2; ++dt) {
#pragma unroll
      for (int qd = 0; qd < 4; ++qd) {
        f32x4 o1 = *reinterpret_cast<const f32x4*>(&cmb[ci + dt * 16 + qd * 4]);
        short4v o4;
#pragma unroll
        for (int e = 0; e < 4; ++e)
          o4[e] = nbf((oacc[dt][4 * qd + e] * a0 + o1[e] * a1) * inv);
        *reinterpret_cast<short4v*>(yp + dt * 32 + qd * 8 + hi * 4) = o4;
      }
    }
  }
}

// ---------------------------------------------------------------------------
extern "C" void kernel_launch(void* const* d_in, const int* in_sizes, int n_in,
                              void* d_out, int out_size, void* d_ws,
                              size_t ws_size, hipStream_t stream) {
  const float* x      = (const float*)d_in[0];
  const float* w_attn = (const float*)d_in[1];
  const float* b_attn = (const float*)d_in[2];
  const float* w_proj = (const float*)d_in[3];
  const float* b_proj = (const float*)d_in[4];
  float* out = (float*)d_out;

  // workspace (bf16 shorts); y reuses xb (dead after QKV GEMM)
  short* xb   = (short*)d_ws;                        // 8192*768
  short* watT = xb + (size_t)M_TOK * CDIM;           // 2304*768
  short* wpT  = watT + (size_t)N_QKV * CDIM;         // 768*768
  short* qkB  = wpT + (size_t)CDIM * CDIM;           // 8192*1536
  short* vtB  = qkB + (size_t)M_TOK * N_QK;          // 24*64*4096
  short* yb   = xb;

  {
    int n = M_TOK * CDIM;
    cast_f32_bf16<<<n / 4 / 256, 256, 0, stream>>>(x, xb, n);
  }
  transpose_cast<<<dim3(N_QKV / 32, CDIM / 32), dim3(32, 8), 0, stream>>>(
      w_attn, watT, CDIM, N_QKV);
  transpose_cast<<<dim3(CDIM / 32, CDIM / 32), dim3(32, 8), 0, stream>>>(
      w_proj, wpT, CDIM, CDIM);

  // qkv = x @ w_attn + b_attn   (Q,K -> qkB; V -> vtB transposed)
  gemm_bt<2><<<dim3(M_TOK / 128, N_QKV / 128), 256, 0, stream>>>(
      xb, watT, b_attn, nullptr, qkB, vtB, M_TOK, N_QKV, CDIM);

  attn_kernel<<<dim3(32, BATCH * NH), 512, 0, stream>>>(qkB, vtB, yb);

  // out = y @ w_proj + b_proj   (f32 out)
  gemm_bt<0><<<dim3(M_TOK / 128, CDIM / 128), 256, 0, stream>>>(
      yb, wpT, b_proj, out, nullptr, nullptr, M_TOK, CDIM, CDIM);
}

// Round 10
// 229.564 us; speedup vs baseline: 4.6301x; 1.4763x over previous
//
#include <hip/hip_runtime.h>

// ---------------------------------------------------------------------------
// CausalSelfAttention (GPT-2 style), MI355X / gfx950
//   qkv GEMM writes Q,K rows and V transposed (vt[bh][d][t])
//   flash attention: swapped-QK^T 32x32x16 MFMA, in-register softmax,
//   8-wave blocks, 2-way split-K, PAIRED q-tiles (heavy+light, 34 iters
//   per block), XCD head-clustering swizzle, defer-rescale (T13),
//   exp2 builtin, tree reductions.
// B=2 T=4096 C=768 H=12 hd=64
// ---------------------------------------------------------------------------

#define DEVFN __device__ __forceinline__

typedef __attribute__((ext_vector_type(8)))  short   short8;
typedef __attribute__((ext_vector_type(4)))  short   short4v;
typedef __attribute__((ext_vector_type(8)))  __bf16  bf16x8;
typedef __attribute__((ext_vector_type(4)))  float   f32x4;
typedef __attribute__((ext_vector_type(16))) float   f32x16;

constexpr int BATCH = 2;
constexpr int T     = 4096;
constexpr int CDIM  = 768;
constexpr int NH    = 12;
constexpr int HD    = 64;
constexpr int M_TOK = BATCH * T;   // 8192
constexpr int N_QKV = 3 * CDIM;    // 2304
constexpr int N_QK  = 2 * CDIM;    // 1536
constexpr float QSCALE = 0.125f * 1.44269504f;  // 1/sqrt(64) * log2(e)

DEVFN short f2bf(float f) {            // RNE float -> bf16 bits
  unsigned u = __builtin_bit_cast(unsigned, f);
  u += 0x7fffu + ((u >> 16) & 1u);
  return (short)(u >> 16);
}
DEVFN float bf2f(short s) {
  return __builtin_bit_cast(float, ((unsigned)(unsigned short)s) << 16);
}
DEVFN short nbf(float f) {             // native cast
  return __builtin_bit_cast(short, (__bf16)f);
}
DEVFN unsigned pack2(float a, float b) {  // 2 f32 -> packed bf16x2
  union { __bf16 h[2]; unsigned u; } x;
  x.h[0] = (__bf16)a; x.h[1] = (__bf16)b;
  return x.u;
}
DEVFN float ex2(float x) { return __builtin_amdgcn_exp2f(x); }
DEVFN f32x4 mfma16(short8 a, short8 b, f32x4 c) {
  return __builtin_amdgcn_mfma_f32_16x16x32_bf16(
      __builtin_bit_cast(bf16x8, a), __builtin_bit_cast(bf16x8, b), c, 0, 0, 0);
}
DEVFN f32x16 mfma32(short8 a, short8 b, f32x16 c) {
  return __builtin_amdgcn_mfma_f32_32x32x16_bf16(
      __builtin_bit_cast(bf16x8, a), __builtin_bit_cast(bf16x8, b), c, 0, 0, 0);
}
DEVFN short8 mk8(unsigned w0, unsigned w1, unsigned w2, unsigned w3) {
  union { unsigned u[4]; short8 s; } x;
  x.u[0] = w0; x.u[1] = w1; x.u[2] = w2; x.u[3] = w3;
  return x.s;
}

// ---------------------------------------------------------------------------
__global__ void cast_f32_bf16(const float* __restrict__ in,
                              short* __restrict__ out, int n) {
  int i = (blockIdx.x * blockDim.x + threadIdx.x) * 4;
  if (i >= n) return;
  f32x4 v = *reinterpret_cast<const f32x4*>(in + i);
  short4v o;
#pragma unroll
  for (int j = 0; j < 4; ++j) o[j] = f2bf(v[j]);
  *reinterpret_cast<short4v*>(out + i) = o;
}

__global__ void transpose_cast(const float* __restrict__ in,
                               short* __restrict__ out, int R, int Cc) {
  __shared__ float tile[32][33];
  int c0 = blockIdx.x * 32, r0 = blockIdx.y * 32;
  int tx = threadIdx.x, ty = threadIdx.y;  // block (32, 8)
#pragma unroll
  for (int j = 0; j < 32; j += 8) {
    int r = r0 + ty + j, c = c0 + tx;
    tile[ty + j][tx] = (r < R && c < Cc) ? in[(size_t)r * Cc + c] : 0.f;
  }
  __syncthreads();
#pragma unroll
  for (int j = 0; j < 32; j += 8) {
    int r = r0 + tx, c = c0 + ty + j;
    if (c < Cc && r < R) out[(size_t)c * R + r] = f2bf(tile[tx][ty + j]);
  }
}

// ---------------------------------------------------------------------------
// GEMM: C[M][N] = A[M][K] @ Bt[N][K]^T + bias[N]
// MODE 0: f32 plain output.
// MODE 2: qkv split — cols [0,1536) -> qk bf16 [M][1536];
//         cols [1536,2304) (= V) -> vt bf16 [(b*NH+h)*64+d][T] (transposed).
// ---------------------------------------------------------------------------
template <int MODE>
__global__ __launch_bounds__(256)
void gemm_bt(const short* __restrict__ A, const short* __restrict__ Bt,
             const float* __restrict__ bias, float* __restrict__ Cf,
             short* __restrict__ qk_out, short* __restrict__ vt_out,
             int M, int N, int K) {
  constexpr int BM = 128, BN = 128, BK = 32, LDP = BK + 8;
  __shared__ short As[BM * LDP];
  __shared__ short Bs[BN * LDP];
  const int bm = blockIdx.x, bn = blockIdx.y;
  const int tid = threadIdx.x;
  const int lane = tid & 63, wid = tid >> 6;
  const int wm = wid >> 1, wn = wid & 1;
  const int lr = lane & 15, lh = lane >> 4;

  f32x4 acc[4][4] = {};

  const short* Abase = A + (size_t)(bm * BM) * K;
  const short* Bbase = Bt + (size_t)(bn * BN) * K;

  for (int k0 = 0; k0 < K; k0 += BK) {
    __syncthreads();
#pragma unroll
    for (int i = 0; i < 2; ++i) {
      int c = tid + i * 256;
      int row = c >> 2, col = (c & 3) << 3;
      *reinterpret_cast<short8*>(&As[row * LDP + col]) =
          *reinterpret_cast<const short8*>(Abase + (size_t)row * K + k0 + col);
      *reinterpret_cast<short8*>(&Bs[row * LDP + col]) =
          *reinterpret_cast<const short8*>(Bbase + (size_t)row * K + k0 + col);
    }
    __syncthreads();

    short8 af[4], bfr[4];
#pragma unroll
    for (int m = 0; m < 4; ++m)
      af[m] = *reinterpret_cast<const short8*>(
          &As[(wm * 64 + m * 16 + lr) * LDP + lh * 8]);
#pragma unroll
    for (int n = 0; n < 4; ++n)
      bfr[n] = *reinterpret_cast<const short8*>(
          &Bs[(wn * 64 + n * 16 + lr) * LDP + lh * 8]);
#pragma unroll
    for (int m = 0; m < 4; ++m)
#pragma unroll
      for (int n = 0; n < 4; ++n)
        acc[m][n] = mfma16(af[m], bfr[n], acc[m][n]);
  }

  // C/D layout: col = lane&15, row = 4*(lane>>4)+r
#pragma unroll
  for (int m = 0; m < 4; ++m) {
#pragma unroll
    for (int n = 0; n < 4; ++n) {
#pragma unroll
      for (int r = 0; r < 4; ++r) {
        int row = bm * BM + wm * 64 + m * 16 + lh * 4 + r;
        int col = bn * BN + wn * 64 + n * 16 + lr;
        float v = acc[m][n][r] + bias[col];
        if (MODE == 0) {
          Cf[(size_t)row * N + col] = v;
        } else {
          if (bn < 12) {  // Q,K region (boundary 1536 is tile-aligned)
            qk_out[(size_t)row * N_QK + col] = f2bf(v);
          } else {        // V region -> transposed store
            int hd_ = col - N_QK;
            int h = hd_ >> 6, d = hd_ & 63;
            int b_ = row >> 12, t_ = row & (T - 1);
            vt_out[(size_t)((b_ * NH + h) * HD + d) * T + t_] = f2bf(v);
          }
        }
      }
    }
  }
}

// ---------------------------------------------------------------------------
// Causal flash attention, swapped-QK^T 32x32, 2-way split-K, PAIRED q-tiles.
// Grid: 384 blocks 1-D. XCD clustering: xcd=blk&7 owns heads 3*xcd..3*xcd+2
// (per-XCD K/V working set 6MB vs 48MB unswizzled). slot=blk>>3:
// bh = xcd*3 + slot%3, bx = slot/3 (0..15).
// Block: 512 thr = 8 waves = 2 k-groups x 4 waves; wave owns 32 q-rows.
// Two phases per block: qb = 31-bx then qb = bx -> 34 k-iters for every
// block (perfect balance). Per phase, group g covers k-tiles
// [g*(qb+1), (g+1)*(qb+1)); flash-decoding combine through LDS per phase.
// Per 64-k tile: register-prefetched staging, S^T = mfma32(K, Q), defer-
// rescale online softmax (T13, THR=8), exp2 builtin, tree reductions,
// P packed to bf16 B-frags via native cvt + shfl_xor + select.
// K[k][d], V^T[d][k] in per-group LDS, XOR-swizzled write+read.
// NOTE launch_bounds 2nd arg — MEASURED: behaves like CUDA min BLOCKS/CU:
// (512,8)->32 VGPR, (512,4)->64 VGPR (spill), (512,2)->no spill. Keep 2.
// ---------------------------------------------------------------------------
__global__ __launch_bounds__(512, 2)
void attn_kernel(const short* __restrict__ qk, const short* __restrict__ vt,
                 short* __restrict__ y) {
  // staging: K[2][4096] shorts @ [0,16384), V[2][4096] @ [16384..)
  // reused per-phase as the split-K combine buffer (9216 floats).
  __shared__ short smem[18432];

  const int blk = blockIdx.x;
  const int xcd = blk & 7, slot = blk >> 3;
  const int bh = xcd * 3 + slot % 3;    // head cluster per XCD
  const int bx = slot / 3;              // 0..15
  const int b = bh / NH, h = bh % NH;
  const int tid = threadIdx.x;
  const int gid = tid >> 8;             // split-K group
  const int tg  = tid & 255;            // thread id within group
  const int wv  = (tid >> 6) & 3;       // wave within group
  const int lane = tid & 63;
  const int c31 = lane & 31, hi = lane >> 5;

  short* Kg = smem + gid * 4096;
  short* Vg = smem + 8192 + gid * 4096;

  const short* qk_b  = qk + (size_t)b * T * N_QK;
  const short* vt_bh = vt + (size_t)(bh * HD) * T;

  // staging geometry: 2 chunks of 16B per thread per tile (per group)
  const int ck0 = tg, ck1 = 256 + tg;
  const int row0 = ck0 >> 3, colB0 = (ck0 & 7) << 4;
  const int row1 = ck1 >> 3, colB1 = (ck1 & 7) << 4;
  const int lsw0 = (row0 * 128 + (colB0 ^ ((row0 & 7) << 4))) >> 1;
  const int lsw1 = (row1 * 128 + (colB1 ^ ((row1 & 7) << 4))) >> 1;
  const short* kp0 = qk_b + (size_t)row0 * N_QK + CDIM + h * HD + (colB0 >> 1);
  const short* kp1 = qk_b + (size_t)row1 * N_QK + CDIM + h * HD + (colB1 >> 1);
  const short* vp0 = vt_bh + (size_t)row0 * T + (colB0 >> 1);
  const short* vp1 = vt_bh + (size_t)row1 * T + (colB1 >> 1);

  const int swq = (c31 & 7) << 4;       // read-side swizzle XOR (bytes)
  float* cmb = reinterpret_cast<float*>(smem);
  const int ci = (wv * 64 + lane) * 36; // combine slot, 16B-aligned

  for (int ph = 0; ph < 2; ++ph) {
    const int qb = ph ? bx : 31 - bx;   // heavy tile first
    const int wq = qb * 128 + wv * 32;  // wave's first q row
    const int qabs = wq + c31;          // lane's q column

    // Q B-frags (lane: q=c31, d = ds*16 + 8*hi + i), scaled by QSCALE
    short8 qf[4];
    {
      const short* qp = qk_b + (size_t)qabs * N_QK + h * HD;
#pragma unroll
      for (int ds = 0; ds < 4; ++ds) {
        short8 raw = *reinterpret_cast<const short8*>(qp + ds * 16 + hi * 8);
#pragma unroll
        for (int i = 0; i < 8; ++i) raw[i] = nbf(bf2f(raw[i]) * QSCALE);
        qf[ds] = raw;
      }
    }

    f32x16 oacc[2];
#pragma unroll
    for (int dt = 0; dt < 2; ++dt)
#pragma unroll
      for (int r = 0; r < 16; ++r) oacc[dt][r] = 0.f;
    float mrow = -1e30f, lrow = 0.f;

    const int half = qb + 1;
    const int base = gid * half;        // this group's first k-tile

    // prologue: prefetch tile `base` into registers
    short8 kreg0 =
        *reinterpret_cast<const short8*>(kp0 + (size_t)base * 64 * N_QK);
    short8 kreg1 =
        *reinterpret_cast<const short8*>(kp1 + (size_t)base * 64 * N_QK);
    short8 vreg0 = *reinterpret_cast<const short8*>(vp0 + base * 64);
    short8 vreg1 = *reinterpret_cast<const short8*>(vp1 + base * 64);

    for (int i = 0; i < half; ++i) {
      const int t = base + i;
      __syncthreads();  // previous readers done; prefetch landed
      *reinterpret_cast<short8*>(&Kg[lsw0]) = kreg0;
      *reinterpret_cast<short8*>(&Kg[lsw1]) = kreg1;
      *reinterpret_cast<short8*>(&Vg[lsw0]) = vreg0;
      *reinterpret_cast<short8*>(&Vg[lsw1]) = vreg1;
      __syncthreads();  // tile visible
      if (i + 1 < half) {  // issue next-tile loads; land during compute
        size_t ko = (size_t)(t + 1) * 64 * N_QK;
        int    vo = (t + 1) * 64;
        kreg0 = *reinterpret_cast<const short8*>(kp0 + ko);
        kreg1 = *reinterpret_cast<const short8*>(kp1 + ko);
        vreg0 = *reinterpret_cast<const short8*>(vp0 + vo);
        vreg1 = *reinterpret_cast<const short8*>(vp1 + vo);
      }

      const int ks = t * 64;
      if (ks > wq + 31) continue;  // wave fully above causal diagonal

      // S^T[64k][32q]: lane holds k-rows ks + 32*kk + (r&3)+8*(r>>2)+4*hi
      f32x16 s0, s1;
#pragma unroll
      for (int r = 0; r < 16; ++r) { s0[r] = 0.f; s1[r] = 0.f; }
#pragma unroll
      for (int ds = 0; ds < 4; ++ds) {
        int cB = (ds * 32 + hi * 16) ^ swq;
        short8 kf0 =
            *reinterpret_cast<const short8*>(&Kg[(c31 * 128 + cB) >> 1]);
        short8 kf1 = *reinterpret_cast<const short8*>(
            &Kg[((32 + c31) * 128 + cB) >> 1]);
        s0 = mfma32(kf0, qf[ds], s0);
        s1 = mfma32(kf1, qf[ds], s1);
      }

      if (ks + 63 > wq) {  // causal mask (wave-uniform branch)
#pragma unroll
        for (int r = 0; r < 16; ++r) {
          int kab = ks + (r & 3) + 8 * (r >> 2) + 4 * hi;
          if (kab > qabs) s0[r] = -1e30f;
          if (kab + 32 > qabs) s1[r] = -1e30f;
        }
      }

      // tree max over 32 values
      float tm[16];
#pragma unroll
      for (int r = 0; r < 16; ++r) tm[r] = fmaxf(s0[r], s1[r]);
#pragma unroll
      for (int off = 8; off >= 1; off >>= 1)
#pragma unroll
        for (int r = 0; r < 8; ++r)
          if (r < off) tm[r] = fmaxf(tm[r], tm[r + off]);
      float mx = fmaxf(tm[0], __shfl_xor(tm[0], 32));

      // T13 defer-rescale: only rescale when max grew by > 8 (exp2 domain)
      if (__any(mx > mrow + 8.f)) {
        float mnew = fmaxf(mrow, mx);
        float alpha = ex2(mrow - mnew);
        mrow = mnew;
        lrow *= alpha;
#pragma unroll
        for (int dt = 0; dt < 2; ++dt)
#pragma unroll
          for (int r = 0; r < 16; ++r) oacc[dt][r] *= alpha;
      }
#pragma unroll
      for (int r = 0; r < 16; ++r) s0[r] = ex2(s0[r] - mrow);
#pragma unroll
      for (int r = 0; r < 16; ++r) s1[r] = ex2(s1[r] - mrow);
      float ts[16];
#pragma unroll
      for (int r = 0; r < 16; ++r) ts[r] = s0[r] + s1[r];
#pragma unroll
      for (int off = 8; off >= 1; off >>= 1)
#pragma unroll
        for (int r = 0; r < 8; ++r)
          if (r < off) ts[r] += ts[r + off];
      lrow += ts[0] + __shfl_xor(ts[0], 32);

      // P -> bf16 PV B-frags (16 k per KT slice). Lane holds (rel):
      //   lo: k0..3 = p[b..b+3], k8..11 = p[b+4..b+7]
      //   hi: k4..7 = p[b..b+3], k12..15 = p[b+4..b+7]
      // word w = (k_{8hi+2w}, k_{8hi+2w+1}):
      //   w0 = hi?partner(C):A   w1 = hi?partner(D):B
      //   w2 = hi?C:partner(A)   w3 = hi?D:partner(B)
#pragma unroll
      for (int KT = 0; KT < 4; ++KT) {
        const f32x16& p = (KT < 2) ? s0 : s1;
        const int bse = (KT & 1) * 8;
        unsigned Aw = pack2(p[bse + 0], p[bse + 1]);
        unsigned Bw = pack2(p[bse + 2], p[bse + 3]);
        unsigned Cw = pack2(p[bse + 4], p[bse + 5]);
        unsigned Dw = pack2(p[bse + 6], p[bse + 7]);
        unsigned As = __shfl_xor(Aw, 32);
        unsigned Bs = __shfl_xor(Bw, 32);
        unsigned Cs = __shfl_xor(Cw, 32);
        unsigned Ds = __shfl_xor(Dw, 32);
        short8 pf =
            mk8(hi ? Cs : Aw, hi ? Ds : Bw, hi ? Cw : As, hi ? Dw : Bs);
        int cB = (KT * 32 + hi * 16) ^ swq;
#pragma unroll
        for (int dt = 0; dt < 2; ++dt) {
          short8 vf = *reinterpret_cast<const short8*>(
              &Vg[((dt * 32 + c31) * 128 + cB) >> 1]);
          oacc[dt] = mfma32(vf, pf, oacc[dt]);
        }
      }
    }

    // ---- split-K combine (flash-decoding merge through LDS) ----
    __syncthreads();  // all staging reads done; smem reusable
    if (gid == 1) {
#pragma unroll
      for (int dt = 0; dt < 2; ++dt)
#pragma unroll
        for (int q4 = 0; q4 < 4; ++q4)
          *reinterpret_cast<f32x4*>(&cmb[ci + dt * 16 + q4 * 4]) = (f32x4){
              oacc[dt][q4 * 4 + 0], oacc[dt][q4 * 4 + 1],
              oacc[dt][q4 * 4 + 2], oacc[dt][q4 * 4 + 3]};
      cmb[ci + 32] = mrow;
      cmb[ci + 33] = lrow;
    }
    __syncthreads();
    if (gid == 0) {
      float m1 = cmb[ci + 32], l1 = cmb[ci + 33];
      float mm = fmaxf(mrow, m1);
      float a0 = ex2(mrow - mm), a1 = ex2(m1 - mm);
      float inv = 1.0f / (lrow * a0 + l1 * a1);
      // epilogue: O^T reg r -> d = dt*32 + (r&3)+8*(r>>2)+4*hi, q = c31
      short* yp = y + (size_t)(b * T + qabs) * CDIM + h * HD;
#pragma unroll
      for (int dt = 0; dt < 2; ++dt) {
#pragma unroll
        for (int qd = 0; qd < 4; ++qd) {
          f32x4 o1 =
              *reinterpret_cast<const f32x4*>(&cmb[ci + dt * 16 + qd * 4]);
          short4v o4;
#pragma unroll
          for (int e = 0; e < 4; ++e)
            o4[e] = nbf((oacc[dt][4 * qd + e] * a0 + o1[e] * a1) * inv);
          *reinterpret_cast<short4v*>(yp + dt * 32 + qd * 8 + hi * 4) = o4;
        }
      }
    }
    // next phase's loop barrier separates cmb reads from staging writes
  }
}

// ---------------------------------------------------------------------------
extern "C" void kernel_launch(void* const* d_in, const int* in_sizes, int n_in,
                              void* d_out, int out_size, void* d_ws,
                              size_t ws_size, hipStream_t stream) {
  const float* x      = (const float*)d_in[0];
  const float* w_attn = (const float*)d_in[1];
  const float* b_attn = (const float*)d_in[2];
  const float* w_proj = (const float*)d_in[3];
  const float* b_proj = (const float*)d_in[4];
  float* out = (float*)d_out;

  // workspace (bf16 shorts); y reuses xb (dead after QKV GEMM)
  short* xb   = (short*)d_ws;                        // 8192*768
  short* watT = xb + (size_t)M_TOK * CDIM;           // 2304*768
  short* wpT  = watT + (size_t)N_QKV * CDIM;         // 768*768
  short* qkB  = wpT + (size_t)CDIM * CDIM;           // 8192*1536
  short* vtB  = qkB + (size_t)M_TOK * N_QK;          // 24*64*4096
  short* yb   = xb;

  {
    int n = M_TOK * CDIM;
    cast_f32_bf16<<<n / 4 / 256, 256, 0, stream>>>(x, xb, n);
  }
  transpose_cast<<<dim3(N_QKV / 32, CDIM / 32), dim3(32, 8), 0, stream>>>(
      w_attn, watT, CDIM, N_QKV);
  transpose_cast<<<dim3(CDIM / 32, CDIM / 32), dim3(32, 8), 0, stream>>>(
      w_proj, wpT, CDIM, CDIM);

  // qkv = x @ w_attn + b_attn   (Q,K -> qkB; V -> vtB transposed)
  gemm_bt<2><<<dim3(M_TOK / 128, N_QKV / 128), 256, 0, stream>>>(
      xb, watT, b_attn, nullptr, qkB, vtB, M_TOK, N_QKV, CDIM);

  attn_kernel<<<dim3(384), 512, 0, stream>>>(qkB, vtB, yb);

  // out = y @ w_proj + b_proj   (f32 out)
  gemm_bt<0><<<dim3(M_TOK / 128, CDIM / 128), 256, 0, stream>>>(
      yb, wpT, b_proj, out, nullptr, nullptr, M_TOK, CDIM, CDIM);
}

// Round 11
// 202.635 us; speedup vs baseline: 5.2454x; 1.1329x over previous
//
#include <hip/hip_runtime.h>

// ---------------------------------------------------------------------------
// CausalSelfAttention (GPT-2 style), MI355X / gfx950
//   qkv GEMM writes Q,K rows and V transposed (vt[bh][d][t])
//   flash attention: swapped-QK^T 32x32x16 MFMA, in-register softmax,
//   768 equal blocks (= 256 CUs x 3) of 4 waves: 2 q-subwaves x 2 split-K
//   groups, paired q-tiles (63-j, j), XCD head clustering, defer-rescale,
//   permlane32_swap P-frags (m214-anchored mapping).
// B=2 T=4096 C=768 H=12 hd=64
// ---------------------------------------------------------------------------

#define DEVFN __device__ __forceinline__

typedef __attribute__((ext_vector_type(8)))  short   short8;
typedef __attribute__((ext_vector_type(4)))  short   short4v;
typedef __attribute__((ext_vector_type(8)))  __bf16  bf16x8;
typedef __attribute__((ext_vector_type(4)))  float   f32x4;
typedef __attribute__((ext_vector_type(16))) float   f32x16;

constexpr int BATCH = 2;
constexpr int T     = 4096;
constexpr int CDIM  = 768;
constexpr int NH    = 12;
constexpr int HD    = 64;
constexpr int M_TOK = BATCH * T;   // 8192
constexpr int N_QKV = 3 * CDIM;    // 2304
constexpr int N_QK  = 2 * CDIM;    // 1536
constexpr float QSCALE = 0.125f * 1.44269504f;  // 1/sqrt(64) * log2(e)

DEVFN short f2bf(float f) {            // RNE float -> bf16 bits
  unsigned u = __builtin_bit_cast(unsigned, f);
  u += 0x7fffu + ((u >> 16) & 1u);
  return (short)(u >> 16);
}
DEVFN float bf2f(short s) {
  return __builtin_bit_cast(float, ((unsigned)(unsigned short)s) << 16);
}
DEVFN short nbf(float f) {             // native cast
  return __builtin_bit_cast(short, (__bf16)f);
}
DEVFN unsigned pack2(float a, float b) {  // 2 f32 -> packed bf16x2
  union { __bf16 h[2]; unsigned u; } x;
  x.h[0] = (__bf16)a; x.h[1] = (__bf16)b;
  return x.u;
}
DEVFN float ex2(float x) { return __builtin_amdgcn_exp2f(x); }
// v_permlane32_swap_b32 a, b: a[32:63] <-> b[0:31] (verified via m214
// recipe: swap(cvtpk(p0,p1), cvtpk(p4,p5)) -> (word0, word2) of B-frag).
DEVFN void pl32swap(unsigned& a, unsigned& b) {
  asm volatile("v_permlane32_swap_b32 %0, %1" : "+v"(a), "+v"(b));
}
DEVFN f32x4 mfma16(short8 a, short8 b, f32x4 c) {
  return __builtin_amdgcn_mfma_f32_16x16x32_bf16(
      __builtin_bit_cast(bf16x8, a), __builtin_bit_cast(bf16x8, b), c, 0, 0, 0);
}
DEVFN f32x16 mfma32(short8 a, short8 b, f32x16 c) {
  return __builtin_amdgcn_mfma_f32_32x32x16_bf16(
      __builtin_bit_cast(bf16x8, a), __builtin_bit_cast(bf16x8, b), c, 0, 0, 0);
}
DEVFN short8 mk8(unsigned w0, unsigned w1, unsigned w2, unsigned w3) {
  union { unsigned u[4]; short8 s; } x;
  x.u[0] = w0; x.u[1] = w1; x.u[2] = w2; x.u[3] = w3;
  return x.s;
}

// ---------------------------------------------------------------------------
__global__ void cast_f32_bf16(const float* __restrict__ in,
                              short* __restrict__ out, int n) {
  int i = (blockIdx.x * blockDim.x + threadIdx.x) * 4;
  if (i >= n) return;
  f32x4 v = *reinterpret_cast<const f32x4*>(in + i);
  short4v o;
#pragma unroll
  for (int j = 0; j < 4; ++j) o[j] = f2bf(v[j]);
  *reinterpret_cast<short4v*>(out + i) = o;
}

__global__ void transpose_cast(const float* __restrict__ in,
                               short* __restrict__ out, int R, int Cc) {
  __shared__ float tile[32][33];
  int c0 = blockIdx.x * 32, r0 = blockIdx.y * 32;
  int tx = threadIdx.x, ty = threadIdx.y;  // block (32, 8)
#pragma unroll
  for (int j = 0; j < 32; j += 8) {
    int r = r0 + ty + j, c = c0 + tx;
    tile[ty + j][tx] = (r < R && c < Cc) ? in[(size_t)r * Cc + c] : 0.f;
  }
  __syncthreads();
#pragma unroll
  for (int j = 0; j < 32; j += 8) {
    int r = r0 + tx, c = c0 + ty + j;
    if (c < Cc && r < R) out[(size_t)c * R + r] = f2bf(tile[tx][ty + j]);
  }
}

// ---------------------------------------------------------------------------
// GEMM: C[M][N] = A[M][K] @ Bt[N][K]^T + bias[N]
// MODE 0: f32 plain output.
// MODE 2: qkv split — cols [0,1536) -> qk bf16 [M][1536];
//         cols [1536,2304) (= V) -> vt bf16 [(b*NH+h)*64+d][T] (transposed).
// ---------------------------------------------------------------------------
template <int MODE>
__global__ __launch_bounds__(256)
void gemm_bt(const short* __restrict__ A, const short* __restrict__ Bt,
             const float* __restrict__ bias, float* __restrict__ Cf,
             short* __restrict__ qk_out, short* __restrict__ vt_out,
             int M, int N, int K) {
  constexpr int BM = 128, BN = 128, BK = 32, LDP = BK + 8;
  __shared__ short As[BM * LDP];
  __shared__ short Bs[BN * LDP];
  const int bm = blockIdx.x, bn = blockIdx.y;
  const int tid = threadIdx.x;
  const int lane = tid & 63, wid = tid >> 6;
  const int wm = wid >> 1, wn = wid & 1;
  const int lr = lane & 15, lh = lane >> 4;

  f32x4 acc[4][4] = {};

  const short* Abase = A + (size_t)(bm * BM) * K;
  const short* Bbase = Bt + (size_t)(bn * BN) * K;

  for (int k0 = 0; k0 < K; k0 += BK) {
    __syncthreads();
#pragma unroll
    for (int i = 0; i < 2; ++i) {
      int c = tid + i * 256;
      int row = c >> 2, col = (c & 3) << 3;
      *reinterpret_cast<short8*>(&As[row * LDP + col]) =
          *reinterpret_cast<const short8*>(Abase + (size_t)row * K + k0 + col);
      *reinterpret_cast<short8*>(&Bs[row * LDP + col]) =
          *reinterpret_cast<const short8*>(Bbase + (size_t)row * K + k0 + col);
    }
    __syncthreads();

    short8 af[4], bfr[4];
#pragma unroll
    for (int m = 0; m < 4; ++m)
      af[m] = *reinterpret_cast<const short8*>(
          &As[(wm * 64 + m * 16 + lr) * LDP + lh * 8]);
#pragma unroll
    for (int n = 0; n < 4; ++n)
      bfr[n] = *reinterpret_cast<const short8*>(
          &Bs[(wn * 64 + n * 16 + lr) * LDP + lh * 8]);
#pragma unroll
    for (int m = 0; m < 4; ++m)
#pragma unroll
      for (int n = 0; n < 4; ++n)
        acc[m][n] = mfma16(af[m], bfr[n], acc[m][n]);
  }

  // C/D layout: col = lane&15, row = 4*(lane>>4)+r
#pragma unroll
  for (int m = 0; m < 4; ++m) {
#pragma unroll
    for (int n = 0; n < 4; ++n) {
#pragma unroll
      for (int r = 0; r < 4; ++r) {
        int row = bm * BM + wm * 64 + m * 16 + lh * 4 + r;
        int col = bn * BN + wn * 64 + n * 16 + lr;
        float v = acc[m][n][r] + bias[col];
        if (MODE == 0) {
          Cf[(size_t)row * N + col] = v;
        } else {
          if (bn < 12) {  // Q,K region (boundary 1536 is tile-aligned)
            qk_out[(size_t)row * N_QK + col] = f2bf(v);
          } else {        // V region -> transposed store
            int hd_ = col - N_QK;
            int h = hd_ >> 6, d = hd_ & 63;
            int b_ = row >> 12, t_ = row & (T - 1);
            vt_out[(size_t)((b_ * NH + h) * HD + d) * T + t_] = f2bf(v);
          }
        }
      }
    }
  }
}

// ---------------------------------------------------------------------------
// Causal flash attention, swapped-QK^T 32x32, split-K x2, 64-row q-tiles.
// Grid: 768 blocks (= 256 CUs x 3, all equal cost). XCD clustering:
// xcd=blk&7 owns heads 3*xcd..3*xcd+2; slot=blk>>3: bh=xcd*3+slot%3,
// j=slot/3 (0..31). Block: 256 thr = 4 waves = 2 k-groups x 2 q-subwaves.
// Two phases: q-tile (64 rows) qt = 63-j then j -> 33+-1 iters per block.
// Per phase, group g covers k-tiles [g*ceil(nt/2) ...); flash-decoding
// combine through LDS. Per 64-k tile: JIT-staged K[k][d] / V^T[d][k]
// (XOR-swizzled write+read, byte ^= (row&7)<<4), S^T = mfma32(K, Q),
// defer-rescale softmax (THR=8), tree reductions, permlane32_swap P-frags.
// NOTE launch_bounds 2nd arg — MEASURED: behaves like CUDA min BLOCKS/CU:
// (512,8)->32 VGPR, (512,4)->64 VGPR (spilled). (256,3) -> cap ~170.
// ---------------------------------------------------------------------------
__global__ __launch_bounds__(256, 3)
void attn_kernel(const short* __restrict__ qk, const short* __restrict__ vt,
                 short* __restrict__ y) {
  // [g0 K | g1 K | g0 V | g1 V], each 64x64 bf16 (4096 shorts). The combine
  // buffer (float, 18KB) overlays this after each phase's k-loop.
  __shared__ short smem[16384];

  const int blk = blockIdx.x;
  const int xcd = blk & 7, slot = blk >> 3;
  const int bh = xcd * 3 + slot % 3;    // head cluster per XCD
  const int j = slot / 3;               // pair index 0..31
  const int b = bh / NH, h = bh % NH;
  const int tid = threadIdx.x;
  const int gid = tid >> 7;             // split-K group
  const int tg  = tid & 127;            // thread id within group
  const int wv2 = (tid >> 6) & 1;       // q-subwave within group
  const int lane = tid & 63;
  const int c31 = lane & 31, hi = lane >> 5;

  short* Kg = smem + gid * 4096;
  short* Vg = smem + 8192 + gid * 4096;

  const short* qk_b  = qk + (size_t)b * T * N_QK;
  const short* vt_bh = vt + (size_t)(bh * HD) * T;

  // staging geometry: 4 K-chunks + 4 V-chunks of 16B per thread per tile
  const short* kp[4];
  const short* vp[4];
  int lsw[4];
#pragma unroll
  for (int c = 0; c < 4; ++c) {
    int ck = tg + c * 128;
    int row = ck >> 3, colB = (ck & 7) << 4;
    lsw[c] = (row * 128 + (colB ^ ((row & 7) << 4))) >> 1;
    kp[c] = qk_b + (size_t)row * N_QK + CDIM + h * HD + (colB >> 1);
    vp[c] = vt_bh + (size_t)row * T + (colB >> 1);
  }

  const int swq = (c31 & 7) << 4;       // read-side swizzle XOR (bytes)
  float* cmb = reinterpret_cast<float*>(smem);
  const int ci = (wv2 * 64 + lane) * 36;  // combine slot, 16B-aligned

  for (int ph = 0; ph < 2; ++ph) {
    const int qt = ph ? j : 63 - j;     // q-tile (64 rows), heavy first
    const int wq = qt * 64 + wv2 * 32;  // wave's first q row
    const int qabs = wq + c31;          // lane's q column

    // Q B-frags (lane: q=c31, d = ds*16 + 8*hi + i), scaled by QSCALE
    short8 qf[4];
    {
      const short* qp = qk_b + (size_t)qabs * N_QK + h * HD;
#pragma unroll
      for (int ds = 0; ds < 4; ++ds) {
        short8 raw = *reinterpret_cast<const short8*>(qp + ds * 16 + hi * 8);
#pragma unroll
        for (int i = 0; i < 8; ++i) raw[i] = nbf(bf2f(raw[i]) * QSCALE);
        qf[ds] = raw;
      }
    }

    f32x16 oacc[2];
#pragma unroll
    for (int dt = 0; dt < 2; ++dt)
#pragma unroll
      for (int r = 0; r < 16; ++r) oacc[dt][r] = 0.f;
    float mrow = -1e30f, lrow = 0.f;

    const int nt = qt + 1;              // causal k-tiles for this q-tile
    const int n0 = (nt + 1) >> 1;       // group 0 tile count (ceil)
    const int ng = gid ? (nt >> 1) : n0;
    const int basei = gid ? n0 : 0;

    for (int i = 0; i < n0; ++i) {      // n0 >= ng for both groups
      const int t = basei + i;
      const bool act = (i < ng);
      short8 kr[4], vr[4];
      if (act) {                        // JIT loads (TLP hides latency)
        size_t ko = (size_t)t * 64 * N_QK;
        int    vo = t * 64;
#pragma unroll
        for (int c = 0; c < 4; ++c) {
          kr[c] = *reinterpret_cast<const short8*>(kp[c] + ko);
          vr[c] = *reinterpret_cast<const short8*>(vp[c] + vo);
        }
      }
      __syncthreads();  // previous tile's readers done
      if (act) {
#pragma unroll
        for (int c = 0; c < 4; ++c) {
          *reinterpret_cast<short8*>(&Kg[lsw[c]]) = kr[c];
          *reinterpret_cast<short8*>(&Vg[lsw[c]]) = vr[c];
        }
      }
      __syncthreads();  // tile visible
      if (!act) continue;

      const int ks = t * 64;
      if (ks > wq + 31) continue;  // wave fully above causal diagonal

      // S^T[64k][32q]: lane holds k-rows ks + 32*kk + (r&3)+8*(r>>2)+4*hi
      f32x16 s0, s1;
#pragma unroll
      for (int r = 0; r < 16; ++r) { s0[r] = 0.f; s1[r] = 0.f; }
#pragma unroll
      for (int ds = 0; ds < 4; ++ds) {
        int cB = (ds * 32 + hi * 16) ^ swq;
        short8 kf0 =
            *reinterpret_cast<const short8*>(&Kg[(c31 * 128 + cB) >> 1]);
        short8 kf1 = *reinterpret_cast<const short8*>(
            &Kg[((32 + c31) * 128 + cB) >> 1]);
        s0 = mfma32(kf0, qf[ds], s0);
        s1 = mfma32(kf1, qf[ds], s1);
      }

      if (ks + 63 > wq) {  // causal mask (wave-uniform branch)
#pragma unroll
        for (int r = 0; r < 16; ++r) {
          int kab = ks + (r & 3) + 8 * (r >> 2) + 4 * hi;
          if (kab > qabs) s0[r] = -1e30f;
          if (kab + 32 > qabs) s1[r] = -1e30f;
        }
      }

      // tree max over 32 values
      float tm[16];
#pragma unroll
      for (int r = 0; r < 16; ++r) tm[r] = fmaxf(s0[r], s1[r]);
#pragma unroll
      for (int off = 8; off >= 1; off >>= 1)
#pragma unroll
        for (int r = 0; r < 8; ++r)
          if (r < off) tm[r] = fmaxf(tm[r], tm[r + off]);
      float mx = fmaxf(tm[0], __shfl_xor(tm[0], 32));

      // T13 defer-rescale: only rescale when max grew by > 8 (exp2 domain)
      if (__any(mx > mrow + 8.f)) {
        float mnew = fmaxf(mrow, mx);
        float alpha = ex2(mrow - mnew);
        mrow = mnew;
        lrow *= alpha;
#pragma unroll
        for (int dt = 0; dt < 2; ++dt)
#pragma unroll
          for (int r = 0; r < 16; ++r) oacc[dt][r] *= alpha;
      }
#pragma unroll
      for (int r = 0; r < 16; ++r) s0[r] = ex2(s0[r] - mrow);
#pragma unroll
      for (int r = 0; r < 16; ++r) s1[r] = ex2(s1[r] - mrow);
      float ts[16];
#pragma unroll
      for (int r = 0; r < 16; ++r) ts[r] = s0[r] + s1[r];
#pragma unroll
      for (int off = 8; off >= 1; off >>= 1)
#pragma unroll
        for (int r = 0; r < 8; ++r)
          if (r < off) ts[r] += ts[r + off];
      lrow += ts[0] + __shfl_xor(ts[0], 32);

      // P -> bf16 PV B-frags via permlane32_swap (m214-anchored):
      // Aw=(p0,p1) Bw=(p2,p3) Cw=(p4,p5) Dw=(p6,p7);
      // swap(Aw,Cw) -> Aw=word0, Cw=word2; swap(Bw,Dw) -> Bw=word1, Dw=word3.
#pragma unroll
      for (int KT = 0; KT < 4; ++KT) {
        const f32x16& p = (KT < 2) ? s0 : s1;
        const int bse = (KT & 1) * 8;
        unsigned Aw = pack2(p[bse + 0], p[bse + 1]);
        unsigned Bw = pack2(p[bse + 2], p[bse + 3]);
        unsigned Cw = pack2(p[bse + 4], p[bse + 5]);
        unsigned Dw = pack2(p[bse + 6], p[bse + 7]);
        pl32swap(Aw, Cw);
        pl32swap(Bw, Dw);
        short8 pf = mk8(Aw, Bw, Cw, Dw);
        int cB = (KT * 32 + hi * 16) ^ swq;
#pragma unroll
        for (int dt = 0; dt < 2; ++dt) {
          short8 vf = *reinterpret_cast<const short8*>(
              &Vg[((dt * 32 + c31) * 128 + cB) >> 1]);
          oacc[dt] = mfma32(vf, pf, oacc[dt]);
        }
      }
    }

    // ---- split-K combine (flash-decoding merge through LDS) ----
    __syncthreads();  // all staging reads done; smem reusable
    if (gid == 1) {
#pragma unroll
      for (int dt = 0; dt < 2; ++dt)
#pragma unroll
        for (int q4 = 0; q4 < 4; ++q4)
          *reinterpret_cast<f32x4*>(&cmb[ci + dt * 16 + q4 * 4]) = (f32x4){
              oacc[dt][q4 * 4 + 0], oacc[dt][q4 * 4 + 1],
              oacc[dt][q4 * 4 + 2], oacc[dt][q4 * 4 + 3]};
      cmb[ci + 32] = mrow;
      cmb[ci + 33] = lrow;
    }
    __syncthreads();
    if (gid == 0) {
      float m1 = cmb[ci + 32], l1 = cmb[ci + 33];
      float mm = fmaxf(mrow, m1);
      float a0 = ex2(mrow - mm), a1 = ex2(m1 - mm);
      float inv = 1.0f / (lrow * a0 + l1 * a1);
      // epilogue: O^T reg r -> d = dt*32 + (r&3)+8*(r>>2)+4*hi, q = c31
      short* yp = y + (size_t)(b * T + qabs) * CDIM + h * HD;
#pragma unroll
      for (int dt = 0; dt < 2; ++dt) {
#pragma unroll
        for (int qd = 0; qd < 4; ++qd) {
          f32x4 o1 =
              *reinterpret_cast<const f32x4*>(&cmb[ci + dt * 16 + qd * 4]);
          short4v o4;
#pragma unroll
          for (int e = 0; e < 4; ++e)
            o4[e] = nbf((oacc[dt][4 * qd + e] * a0 + o1[e] * a1) * inv);
          *reinterpret_cast<short4v*>(yp + dt * 32 + qd * 8 + hi * 4) = o4;
        }
      }
    }
    // next phase's first barrier separates cmb reads from staging writes
  }
}

// ---------------------------------------------------------------------------
extern "C" void kernel_launch(void* const* d_in, const int* in_sizes, int n_in,
                              void* d_out, int out_size, void* d_ws,
                              size_t ws_size, hipStream_t stream) {
  const float* x      = (const float*)d_in[0];
  const float* w_attn = (const float*)d_in[1];
  const float* b_attn = (const float*)d_in[2];
  const float* w_proj = (const float*)d_in[3];
  const float* b_proj = (const float*)d_in[4];
  float* out = (float*)d_out;

  // workspace (bf16 shorts); y reuses xb (dead after QKV GEMM)
  short* xb   = (short*)d_ws;                        // 8192*768
  short* watT = xb + (size_t)M_TOK * CDIM;           // 2304*768
  short* wpT  = watT + (size_t)N_QKV * CDIM;         // 768*768
  short* qkB  = wpT + (size_t)CDIM * CDIM;           // 8192*1536
  short* vtB  = qkB + (size_t)M_TOK * N_QK;          // 24*64*4096
  short* yb   = xb;

  {
    int n = M_TOK * CDIM;
    cast_f32_bf16<<<n / 4 / 256, 256, 0, stream>>>(x, xb, n);
  }
  transpose_cast<<<dim3(N_QKV / 32, CDIM / 32), dim3(32, 8), 0, stream>>>(
      w_attn, watT, CDIM, N_QKV);
  transpose_cast<<<dim3(CDIM / 32, CDIM / 32), dim3(32, 8), 0, stream>>>(
      w_proj, wpT, CDIM, CDIM);

  // qkv = x @ w_attn + b_attn   (Q,K -> qkB; V -> vtB transposed)
  gemm_bt<2><<<dim3(M_TOK / 128, N_QKV / 128), 256, 0, stream>>>(
      xb, watT, b_attn, nullptr, qkB, vtB, M_TOK, N_QKV, CDIM);

  attn_kernel<<<dim3(768), 256, 0, stream>>>(qkB, vtB, yb);

  // out = y @ w_proj + b_proj   (f32 out)
  gemm_bt<0><<<dim3(M_TOK / 128, CDIM / 128), 256, 0, stream>>>(
      yb, wpT, b_proj, out, nullptr, nullptr, M_TOK, CDIM, CDIM);
}

// Round 12
// 198.727 us; speedup vs baseline: 5.3486x; 1.0197x over previous
//
#include <hip/hip_runtime.h>

// ---------------------------------------------------------------------------
// CausalSelfAttention (GPT-2 style), MI355X / gfx950
//   qkv GEMM (m97-style global_load_lds + swizzled LDS) -> Q,K rows + V rows
//   vtrans: V -> vt[bh][d][t] (coalesced 64x64 LDS transpose)
//   flash attention: swapped-QK^T 32x32x16, split-K x2, 768 equal blocks
//   proj GEMM f32 out
// B=2 T=4096 C=768 H=12 hd=64
// ---------------------------------------------------------------------------

#define DEVFN __device__ __forceinline__

typedef __attribute__((ext_vector_type(8)))  short   short8;
typedef __attribute__((ext_vector_type(4)))  short   short4v;
typedef __attribute__((ext_vector_type(8)))  __bf16  bf16x8;
typedef __attribute__((ext_vector_type(4)))  float   f32x4;
typedef __attribute__((ext_vector_type(16))) float   f32x16;

constexpr int BATCH = 2;
constexpr int T     = 4096;
constexpr int CDIM  = 768;
constexpr int NH    = 12;
constexpr int HD    = 64;
constexpr int M_TOK = BATCH * T;   // 8192
constexpr int N_QKV = 3 * CDIM;    // 2304
constexpr int N_QK  = 2 * CDIM;    // 1536
constexpr float QSCALE = 0.125f * 1.44269504f;  // 1/sqrt(64) * log2(e)

DEVFN short f2bf(float f) {            // RNE float -> bf16 bits
  unsigned u = __builtin_bit_cast(unsigned, f);
  u += 0x7fffu + ((u >> 16) & 1u);
  return (short)(u >> 16);
}
DEVFN float bf2f(short s) {
  return __builtin_bit_cast(float, ((unsigned)(unsigned short)s) << 16);
}
DEVFN short nbf(float f) {             // native cast
  return __builtin_bit_cast(short, (__bf16)f);
}
DEVFN unsigned pack2(float a, float b) {  // 2 f32 -> packed bf16x2
  union { __bf16 h[2]; unsigned u; } x;
  x.h[0] = (__bf16)a; x.h[1] = (__bf16)b;
  return x.u;
}
DEVFN float ex2(float x) { return __builtin_amdgcn_exp2f(x); }
// v_permlane32_swap_b32 a, b: a[32:63] <-> b[0:31] (R11-verified mapping).
DEVFN void pl32swap(unsigned& a, unsigned& b) {
  asm volatile("v_permlane32_swap_b32 %0, %1" : "+v"(a), "+v"(b));
}
DEVFN f32x4 mfma16(short8 a, short8 b, f32x4 c) {
  return __builtin_amdgcn_mfma_f32_16x16x32_bf16(
      __builtin_bit_cast(bf16x8, a), __builtin_bit_cast(bf16x8, b), c, 0, 0, 0);
}
DEVFN f32x16 mfma32(short8 a, short8 b, f32x16 c) {
  return __builtin_amdgcn_mfma_f32_32x32x16_bf16(
      __builtin_bit_cast(bf16x8, a), __builtin_bit_cast(bf16x8, b), c, 0, 0, 0);
}
DEVFN short8 mk8(unsigned w0, unsigned w1, unsigned w2, unsigned w3) {
  union { unsigned u[4]; short8 s; } x;
  x.u[0] = w0; x.u[1] = w1; x.u[2] = w2; x.u[3] = w3;
  return x.s;
}
DEVFN void gload16(const short* g, short* l) {   // async 16B global->LDS
  __builtin_amdgcn_global_load_lds(
      (const __attribute__((address_space(1))) void*)g,
      (__attribute__((address_space(3))) void*)l, 16, 0, 0);
}

// ---------------------------------------------------------------------------
__global__ void cast_f32_bf16(const float* __restrict__ in,
                              short* __restrict__ out, int n) {
  int i = (blockIdx.x * blockDim.x + threadIdx.x) * 4;
  if (i >= n) return;
  f32x4 v = *reinterpret_cast<const f32x4*>(in + i);
  short4v o;
#pragma unroll
  for (int j = 0; j < 4; ++j) o[j] = f2bf(v[j]);
  *reinterpret_cast<short4v*>(out + i) = o;
}

__global__ void transpose_cast(const float* __restrict__ in,
                               short* __restrict__ out, int R, int Cc) {
  __shared__ float tile[32][33];
  int c0 = blockIdx.x * 32, r0 = blockIdx.y * 32;
  int tx = threadIdx.x, ty = threadIdx.y;  // block (32, 8)
#pragma unroll
  for (int j = 0; j < 32; j += 8) {
    int r = r0 + ty + j, c = c0 + tx;
    tile[ty + j][tx] = (r < R && c < Cc) ? in[(size_t)r * Cc + c] : 0.f;
  }
  __syncthreads();
#pragma unroll
  for (int j = 0; j < 32; j += 8) {
    int r = r0 + tx, c = c0 + ty + j;
    if (c < Cc && r < R) out[(size_t)c * R + r] = f2bf(tile[tx][ty + j]);
  }
}

// v [B*T][768] bf16 -> vt [(b*NH+h)*HD+d][T] bf16; 64x64 tiles, coalesced.
__global__ void vtrans(const short* __restrict__ v, short* __restrict__ vt) {
  __shared__ short t_lds[64 * 72];  // [d][t], pad 72 (bank-spread)
  const int t0 = blockIdx.x * 64;
  const int bh = blockIdx.y;
  const int b = bh / NH, h = bh % NH;
  const int tid = threadIdx.x;  // 256
#pragma unroll
  for (int j = 0; j < 2; ++j) {
    int c = j * 256 + tid;
    int tr = c >> 3, dc = (c & 7) << 3;
    short8 vv = *reinterpret_cast<const short8*>(
        v + (size_t)(b * T + t0 + tr) * CDIM + h * HD + dc);
#pragma unroll
    for (int e = 0; e < 8; ++e) t_lds[(dc + e) * 72 + tr] = vv[e];
  }
  __syncthreads();
#pragma unroll
  for (int j = 0; j < 2; ++j) {
    int c = j * 256 + tid;
    int d = c >> 3, tc = (c & 7) << 3;
    short8 o = *reinterpret_cast<const short8*>(&t_lds[d * 72 + tc]);
    *reinterpret_cast<short8*>(vt + (size_t)(bh * HD + d) * T + t0 + tc) = o;
  }
}

// ---------------------------------------------------------------------------
// GEMM: C[M][N] = A[M][K] @ Bt[N][K]^T + bias[N]
// m97 structure: global_load_lds (16B) staging into LINEAR LDS with a
// source-side XOR swizzle (key = line&7 on 128B lines); ds_read_b128 frag
// reads apply the same key -> <=2-way bank conflicts (free).
// MODE 0: f32 plain output. MODE 2: cols [0,1536) -> qk bf16 [M][1536];
// cols [1536,2304) -> v bf16 [M][768] (plain rows; vtrans transposes later).
// ---------------------------------------------------------------------------
template <int MODE>
__global__ __launch_bounds__(256)
void gemm_bt(const short* __restrict__ A, const short* __restrict__ Bt,
             const float* __restrict__ bias, float* __restrict__ Cf,
             short* __restrict__ qk_out, short* __restrict__ v_out,
             int M, int N, int K) {
  constexpr int BM = 128, BN = 128, BK = 32;
  __shared__ short As[BM * BK];   // linear [128 rows][32 shorts], swizzled
  __shared__ short Bs[BN * BK];
  const int bm = blockIdx.x, bn = blockIdx.y;
  const int tid = threadIdx.x;
  const int lane = tid & 63, wid = tid >> 6;
  const int wm = wid >> 1, wn = wid & 1;
  const int lr = lane & 15, lh = lane >> 4;

  f32x4 acc[4][4] = {};

  const short* Abase = A + (size_t)(bm * BM) * K;
  const short* Bbase = Bt + (size_t)(bn * BN) * K;

  // staging source geometry: LDS chunk c = j*256+tid; line=c>>3, p=c&7;
  // logical q = p ^ (line&7); row = 2*line + (q>>2); col = (q&3)*8 shorts.
  int srow[2], scol[2];
#pragma unroll
  for (int j = 0; j < 2; ++j) {
    int c = j * 256 + tid;
    int line = c >> 3, p = c & 7;
    int q = p ^ (line & 7);
    srow[j] = line * 2 + (q >> 2);
    scol[j] = (q & 3) << 3;
  }

  for (int k0 = 0; k0 < K; k0 += BK) {
    __syncthreads();
#pragma unroll
    for (int j = 0; j < 2; ++j) {  // dest: wave-uniform base + lane*16B
      gload16(Abase + (size_t)srow[j] * K + k0 + scol[j],
              &As[(j * 256 + wid * 64) * 8]);
      gload16(Bbase + (size_t)srow[j] * K + k0 + scol[j],
              &Bs[(j * 256 + wid * 64) * 8]);
    }
    __syncthreads();  // compiler drains vmcnt(0) before barrier

    short8 af[4], bfr[4];
#pragma unroll
    for (int m = 0; m < 4; ++m) {
      int r = wm * 64 + m * 16 + lr;
      int p = (((r & 1) << 2) + lh) ^ ((r >> 1) & 7);
      af[m] = *reinterpret_cast<const short8*>(&As[(r >> 1) * 64 + p * 8]);
    }
#pragma unroll
    for (int n = 0; n < 4; ++n) {
      int r = wn * 64 + n * 16 + lr;
      int p = (((r & 1) << 2) + lh) ^ ((r >> 1) & 7);
      bfr[n] = *reinterpret_cast<const short8*>(&Bs[(r >> 1) * 64 + p * 8]);
    }
#pragma unroll
    for (int m = 0; m < 4; ++m)
#pragma unroll
      for (int n = 0; n < 4; ++n)
        acc[m][n] = mfma16(af[m], bfr[n], acc[m][n]);
  }

  // C/D layout: col = lane&15, row = 4*(lane>>4)+r
#pragma unroll
  for (int m = 0; m < 4; ++m) {
#pragma unroll
    for (int n = 0; n < 4; ++n) {
#pragma unroll
      for (int r = 0; r < 4; ++r) {
        int row = bm * BM + wm * 64 + m * 16 + lh * 4 + r;
        int col = bn * BN + wn * 64 + n * 16 + lr;
        float v = acc[m][n][r] + bias[col];
        if (MODE == 0) {
          Cf[(size_t)row * N + col] = v;
        } else {
          if (bn < 12) {  // Q,K region (boundary 1536 is tile-aligned)
            qk_out[(size_t)row * N_QK + col] = f2bf(v);
          } else {        // V region -> plain rows (vtrans handles layout)
            v_out[(size_t)row * CDIM + (col - N_QK)] = f2bf(v);
          }
        }
      }
    }
  }
}

// ---------------------------------------------------------------------------
// Causal flash attention (unchanged from round 11).
// Grid: 768 blocks (= 256 CUs x 3, all equal cost). XCD clustering:
// xcd=blk&7 owns heads 3*xcd..3*xcd+2; slot=blk>>3: bh=xcd*3+slot%3,
// j=slot/3 (0..31). Block: 256 thr = 4 waves = 2 k-groups x 2 q-subwaves.
// Two phases: q-tile (64 rows) qt = 63-j then j. Split-K flash-decoding
// combine through LDS. JIT-staged K[k][d]/V^T[d][k], XOR-swizzled, swapped
// QK^T mfma32, defer-rescale softmax, permlane32_swap P-frags.
// NOTE launch_bounds 2nd arg — MEASURED: behaves like CUDA min BLOCKS/CU:
// (512,8)->32 VGPR, (512,4)->64 VGPR (spilled). (256,3) -> cap ~170.
// ---------------------------------------------------------------------------
__global__ __launch_bounds__(256, 3)
void attn_kernel(const short* __restrict__ qk, const short* __restrict__ vt,
                 short* __restrict__ y) {
  __shared__ short smem[16384];

  const int blk = blockIdx.x;
  const int xcd = blk & 7, slot = blk >> 3;
  const int bh = xcd * 3 + slot % 3;    // head cluster per XCD
  const int j = slot / 3;               // pair index 0..31
  const int b = bh / NH, h = bh % NH;
  const int tid = threadIdx.x;
  const int gid = tid >> 7;             // split-K group
  const int tg  = tid & 127;
  const int wv2 = (tid >> 6) & 1;       // q-subwave within group
  const int lane = tid & 63;
  const int c31 = lane & 31, hi = lane >> 5;

  short* Kg = smem + gid * 4096;
  short* Vg = smem + 8192 + gid * 4096;

  const short* qk_b  = qk + (size_t)b * T * N_QK;
  const short* vt_bh = vt + (size_t)(bh * HD) * T;

  const short* kp[4];
  const short* vp[4];
  int lsw[4];
#pragma unroll
  for (int c = 0; c < 4; ++c) {
    int ck = tg + c * 128;
    int row = ck >> 3, colB = (ck & 7) << 4;
    lsw[c] = (row * 128 + (colB ^ ((row & 7) << 4))) >> 1;
    kp[c] = qk_b + (size_t)row * N_QK + CDIM + h * HD + (colB >> 1);
    vp[c] = vt_bh + (size_t)row * T + (colB >> 1);
  }

  const int swq = (c31 & 7) << 4;
  float* cmb = reinterpret_cast<float*>(smem);
  const int ci = (wv2 * 64 + lane) * 36;

  for (int ph = 0; ph < 2; ++ph) {
    const int qt = ph ? j : 63 - j;
    const int wq = qt * 64 + wv2 * 32;
    const int qabs = wq + c31;

    short8 qf[4];
    {
      const short* qp = qk_b + (size_t)qabs * N_QK + h * HD;
#pragma unroll
      for (int ds = 0; ds < 4; ++ds) {
        short8 raw = *reinterpret_cast<const short8*>(qp + ds * 16 + hi * 8);
#pragma unroll
        for (int i = 0; i < 8; ++i) raw[i] = nbf(bf2f(raw[i]) * QSCALE);
        qf[ds] = raw;
      }
    }

    f32x16 oacc[2];
#pragma unroll
    for (int dt = 0; dt < 2; ++dt)
#pragma unroll
      for (int r = 0; r < 16; ++r) oacc[dt][r] = 0.f;
    float mrow = -1e30f, lrow = 0.f;

    const int nt = qt + 1;
    const int n0 = (nt + 1) >> 1;
    const int ng = gid ? (nt >> 1) : n0;
    const int basei = gid ? n0 : 0;

    for (int i = 0; i < n0; ++i) {
      const int t = basei + i;
      const bool act = (i < ng);
      short8 kr[4], vr[4];
      if (act) {
        size_t ko = (size_t)t * 64 * N_QK;
        int    vo = t * 64;
#pragma unroll
        for (int c = 0; c < 4; ++c) {
          kr[c] = *reinterpret_cast<const short8*>(kp[c] + ko);
          vr[c] = *reinterpret_cast<const short8*>(vp[c] + vo);
        }
      }
      __syncthreads();
      if (act) {
#pragma unroll
        for (int c = 0; c < 4; ++c) {
          *reinterpret_cast<short8*>(&Kg[lsw[c]]) = kr[c];
          *reinterpret_cast<short8*>(&Vg[lsw[c]]) = vr[c];
        }
      }
      __syncthreads();
      if (!act) continue;

      const int ks = t * 64;
      if (ks > wq + 31) continue;

      f32x16 s0, s1;
#pragma unroll
      for (int r = 0; r < 16; ++r) { s0[r] = 0.f; s1[r] = 0.f; }
#pragma unroll
      for (int ds = 0; ds < 4; ++ds) {
        int cB = (ds * 32 + hi * 16) ^ swq;
        short8 kf0 =
            *reinterpret_cast<const short8*>(&Kg[(c31 * 128 + cB) >> 1]);
        short8 kf1 = *reinterpret_cast<const short8*>(
            &Kg[((32 + c31) * 128 + cB) >> 1]);
        s0 = mfma32(kf0, qf[ds], s0);
        s1 = mfma32(kf1, qf[ds], s1);
      }

      if (ks + 63 > wq) {
#pragma unroll
        for (int r = 0; r < 16; ++r) {
          int kab = ks + (r & 3) + 8 * (r >> 2) + 4 * hi;
          if (kab > qabs) s0[r] = -1e30f;
          if (kab + 32 > qabs) s1[r] = -1e30f;
        }
      }

      float tm[16];
#pragma unroll
      for (int r = 0; r < 16; ++r) tm[r] = fmaxf(s0[r], s1[r]);
#pragma unroll
      for (int off = 8; off >= 1; off >>= 1)
#pragma unroll
        for (int r = 0; r < 8; ++r)
          if (r < off) tm[r] = fmaxf(tm[r], tm[r + off]);
      float mx = fmaxf(tm[0], __shfl_xor(tm[0], 32));

      if (__any(mx > mrow + 8.f)) {
        float mnew = fmaxf(mrow, mx);
        float alpha = ex2(mrow - mnew);
        mrow = mnew;
        lrow *= alpha;
#pragma unroll
        for (int dt = 0; dt < 2; ++dt)
#pragma unroll
          for (int r = 0; r < 16; ++r) oacc[dt][r] *= alpha;
      }
#pragma unroll
      for (int r = 0; r < 16; ++r) s0[r] = ex2(s0[r] - mrow);
#pragma unroll
      for (int r = 0; r < 16; ++r) s1[r] = ex2(s1[r] - mrow);
      float ts[16];
#pragma unroll
      for (int r = 0; r < 16; ++r) ts[r] = s0[r] + s1[r];
#pragma unroll
      for (int off = 8; off >= 1; off >>= 1)
#pragma unroll
        for (int r = 0; r < 8; ++r)
          if (r < off) ts[r] += ts[r + off];
      lrow += ts[0] + __shfl_xor(ts[0], 32);

#pragma unroll
      for (int KT = 0; KT < 4; ++KT) {
        const f32x16& p = (KT < 2) ? s0 : s1;
        const int bse = (KT & 1) * 8;
        unsigned Aw = pack2(p[bse + 0], p[bse + 1]);
        unsigned Bw = pack2(p[bse + 2], p[bse + 3]);
        unsigned Cw = pack2(p[bse + 4], p[bse + 5]);
        unsigned Dw = pack2(p[bse + 6], p[bse + 7]);
        pl32swap(Aw, Cw);
        pl32swap(Bw, Dw);
        short8 pf = mk8(Aw, Bw, Cw, Dw);
        int cB = (KT * 32 + hi * 16) ^ swq;
#pragma unroll
        for (int dt = 0; dt < 2; ++dt) {
          short8 vf = *reinterpret_cast<const short8*>(
              &Vg[((dt * 32 + c31) * 128 + cB) >> 1]);
          oacc[dt] = mfma32(vf, pf, oacc[dt]);
        }
      }
    }

    // ---- split-K combine ----
    __syncthreads();
    if (gid == 1) {
#pragma unroll
      for (int dt = 0; dt < 2; ++dt)
#pragma unroll
        for (int q4 = 0; q4 < 4; ++q4)
          *reinterpret_cast<f32x4*>(&cmb[ci + dt * 16 + q4 * 4]) = (f32x4){
              oacc[dt][q4 * 4 + 0], oacc[dt][q4 * 4 + 1],
              oacc[dt][q4 * 4 + 2], oacc[dt][q4 * 4 + 3]};
      cmb[ci + 32] = mrow;
      cmb[ci + 33] = lrow;
    }
    __syncthreads();
    if (gid == 0) {
      float m1 = cmb[ci + 32], l1 = cmb[ci + 33];
      float mm = fmaxf(mrow, m1);
      float a0 = ex2(mrow - mm), a1 = ex2(m1 - mm);
      float inv = 1.0f / (lrow * a0 + l1 * a1);
      short* yp = y + (size_t)(b * T + qabs) * CDIM + h * HD;
#pragma unroll
      for (int dt = 0; dt < 2; ++dt) {
#pragma unroll
        for (int qd = 0; qd < 4; ++qd) {
          f32x4 o1 =
              *reinterpret_cast<const f32x4*>(&cmb[ci + dt * 16 + qd * 4]);
          short4v o4;
#pragma unroll
          for (int e = 0; e < 4; ++e)
            o4[e] = nbf((oacc[dt][4 * qd + e] * a0 + o1[e] * a1) * inv);
          *reinterpret_cast<short4v*>(yp + dt * 32 + qd * 8 + hi * 4) = o4;
        }
      }
    }
  }
}

// ---------------------------------------------------------------------------
extern "C" void kernel_launch(void* const* d_in, const int* in_sizes, int n_in,
                              void* d_out, int out_size, void* d_ws,
                              size_t ws_size, hipStream_t stream) {
  const float* x      = (const float*)d_in[0];
  const float* w_attn = (const float*)d_in[1];
  const float* b_attn = (const float*)d_in[2];
  const float* w_proj = (const float*)d_in[3];
  const float* b_proj = (const float*)d_in[4];
  float* out = (float*)d_out;

  // workspace (bf16 shorts); y reuses xb (dead after QKV GEMM)
  short* xb   = (short*)d_ws;                        // 8192*768
  short* watT = xb + (size_t)M_TOK * CDIM;           // 2304*768
  short* wpT  = watT + (size_t)N_QKV * CDIM;         // 768*768
  short* qkB  = wpT + (size_t)CDIM * CDIM;           // 8192*1536
  short* vB   = qkB + (size_t)M_TOK * N_QK;          // 8192*768
  short* vtB  = vB + (size_t)M_TOK * CDIM;           // 24*64*4096
  short* yb   = xb;

  {
    int n = M_TOK * CDIM;
    cast_f32_bf16<<<n / 4 / 256, 256, 0, stream>>>(x, xb, n);
  }
  transpose_cast<<<dim3(N_QKV / 32, CDIM / 32), dim3(32, 8), 0, stream>>>(
      w_attn, watT, CDIM, N_QKV);
  transpose_cast<<<dim3(CDIM / 32, CDIM / 32), dim3(32, 8), 0, stream>>>(
      w_proj, wpT, CDIM, CDIM);

  // qkv = x @ w_attn + b_attn   (Q,K -> qkB; V -> vB plain)
  gemm_bt<2><<<dim3(M_TOK / 128, N_QKV / 128), 256, 0, stream>>>(
      xb, watT, b_attn, nullptr, qkB, vB, M_TOK, N_QKV, CDIM);

  // vt[bh][d][t] <- v
  vtrans<<<dim3(T / 64, BATCH * NH), 256, 0, stream>>>(vB, vtB);

  attn_kernel<<<dim3(768), 256, 0, stream>>>(qkB, vtB, yb);

  // out = y @ w_proj + b_proj   (f32 out)
  gemm_bt<0><<<dim3(M_TOK / 128, CDIM / 128), 256, 0, stream>>>(
      yb, wpT, b_proj, out, nullptr, nullptr, M_TOK, CDIM, CDIM);
}